// Round 1
// baseline (506.639 us; speedup 1.0000x reference)
//
#include <hip/hip_runtime.h>
#include <math.h>

// Problem constants (fixed by the reference)
#define NB   256                 // graphs
#define NPG  256                 // nodes per graph
#define NN   (NB * NPG)          // 65536 nodes
#define NE   (NN * 16)           // 1048576 edges
#define EPG  (NE / NB)           // 4096 edges per graph
#define FD   128                 // F == H
#define NC   10

// ---------------------------------------------------------------------------
// init: nmask = 1, active_list = iota, z = 0  (z has NB*2*FD == NN elements)
// ---------------------------------------------------------------------------
__global__ void k_init(float* __restrict__ nmask, int* __restrict__ alist,
                       float* __restrict__ z) {
    int i = blockIdx.x * 256 + threadIdx.x;
    nmask[i] = 1.f;
    alist[i] = i;
    z[i] = 0.f;
}

// ---------------------------------------------------------------------------
// CSR-by-dst build, one block per graph (edges are graph-contiguous).
// LDS counting sort: count -> exclusive scan -> scatter.
// ---------------------------------------------------------------------------
__global__ __launch_bounds__(NPG)
void k_csr(const int* __restrict__ ei, int* __restrict__ row_ptr,
           int* __restrict__ colI) {
    const int g = blockIdx.x, t = threadIdx.x;
    const int* __restrict__ srcA = ei;
    const int* __restrict__ dstA = ei + NE;
    __shared__ int cnt[NPG];
    __shared__ int sc[NPG];
    __shared__ int off[NPG];
    cnt[t] = 0;
    __syncthreads();
    const int base = g * EPG;
    for (int e = t; e < EPG; e += NPG)
        atomicAdd(&cnt[dstA[base + e] - g * NPG], 1);
    __syncthreads();
    sc[t] = cnt[t];
    __syncthreads();
    for (int o = 1; o < NPG; o <<= 1) {
        int add = (t >= o) ? sc[t - o] : 0;
        __syncthreads();
        sc[t] += add;
        __syncthreads();
    }
    int excl = sc[t] - cnt[t];
    row_ptr[g * NPG + t] = base + excl;
    if (g == 0 && t == 0) row_ptr[NN] = NE;
    off[t] = excl;
    __syncthreads();
    for (int e = t; e < EPG; e += NPG) {
        int d = dstA[base + e] - g * NPG;
        int p = atomicAdd(&off[d], 1);
        colI[base + p] = srcA[base + e];
    }
}

// ---------------------------------------------------------------------------
// Row-gathered GEMM: Y[v] = X[v] @ W  for v in rows[0..nrows)
// 4 rows per 128-thread block; X rows staged in LDS (broadcast reads).
// ---------------------------------------------------------------------------
__global__ __launch_bounds__(128)
void k_gemm(const float* __restrict__ X, const float* __restrict__ W,
            const int* __restrict__ rows, int nrows, float* __restrict__ Y) {
    const int t = threadIdx.x;
    const int rb = blockIdx.x * 4;
    __shared__ float xs[4][FD];
    int vidx[4];
#pragma unroll
    for (int r = 0; r < 4; ++r) {
        int rr = rb + r;
        int v = (rr < nrows) ? rows[rr] : -1;
        vidx[r] = v;
        xs[r][t] = (v >= 0) ? X[(size_t)v * FD + t] : 0.f;
    }
    __syncthreads();
    float a0 = 0.f, a1 = 0.f, a2 = 0.f, a3 = 0.f;
#pragma unroll 8
    for (int k = 0; k < FD; ++k) {
        float w = W[k * FD + t];
        a0 += xs[0][k] * w;
        a1 += xs[1][k] * w;
        a2 += xs[2][k] * w;
        a3 += xs[3][k] * w;
    }
    if (vidx[0] >= 0) Y[(size_t)vidx[0] * FD + t] = a0;
    if (vidx[1] >= 0) Y[(size_t)vidx[1] * FD + t] = a1;
    if (vidx[2] >= 0) Y[(size_t)vidx[2] * FD + t] = a2;
    if (vidx[3] >= 0) Y[(size_t)vidx[3] * FD + t] = a3;
}

// ---------------------------------------------------------------------------
// dinv[v] = nmask[v] ? rsqrt(1 + sum_{in-edges} nmask[src]) : 0   (all N nodes)
// ---------------------------------------------------------------------------
__global__ void k_dinv(const float* __restrict__ nmask,
                       const int* __restrict__ row_ptr,
                       const int* __restrict__ colI, float* __restrict__ dinv) {
    int v = blockIdx.x * 256 + threadIdx.x;
    float dv = 0.f;
    if (nmask[v] > 0.f) {
        float sum = 1.f;
        int e0 = row_ptr[v], e1 = row_ptr[v + 1];
        for (int e = e0; e < e1; ++e) sum += nmask[colI[e]];
        dv = rsqrtf(sum);
    }
    dinv[v] = dv;
}

// ---------------------------------------------------------------------------
// Main conv finalize: h[v] = relu( sum_e w*hW[src] + hW[v]*dinv^2 + b ),
// one block (128 threads = feature dim) per active node.
// ---------------------------------------------------------------------------
__global__ __launch_bounds__(128)
void k_conv(const float* __restrict__ hW, const float* __restrict__ dinv,
            const int* __restrict__ row_ptr, const int* __restrict__ colI,
            const int* __restrict__ rows, const float* __restrict__ bias,
            float* __restrict__ outH) {
    const int v = rows[blockIdx.x];
    const int t = threadIdx.x;
    const float dv = dinv[v];
    float acc = hW[(size_t)v * FD + t] * dv * dv + bias[t];
    const int e0 = row_ptr[v], e1 = row_ptr[v + 1];
    for (int e = e0; e < e1; ++e) {
        int u = colI[e];
        float w = dinv[u] * dv;
        if (w > 0.f) acc += w * hW[(size_t)u * FD + t];
    }
    outH[(size_t)v * FD + t] = fmaxf(acc, 0.f);
}

// ---------------------------------------------------------------------------
// Score matvec: sW[v] = dot(h[v], Wp). One wave per node (4 waves/block).
// ---------------------------------------------------------------------------
__global__ __launch_bounds__(256)
void k_smatvec(const float* __restrict__ h, const float* __restrict__ Wp,
               const int* __restrict__ rows, int nrows, float* __restrict__ sW) {
    int wid = blockIdx.x * 4 + (threadIdx.x >> 6);
    int lane = threadIdx.x & 63;
    if (wid >= nrows) return;
    int v = rows[wid];
    float a = h[(size_t)v * FD + lane] * Wp[lane] +
              h[(size_t)v * FD + 64 + lane] * Wp[64 + lane];
#pragma unroll
    for (int o = 32; o > 0; o >>= 1) a += __shfl_xor(a, o);
    if (lane == 0) sW[v] = a;
}

// ---------------------------------------------------------------------------
// Score conv: s[v] = sum_e w*sW[src] + sW[v]*dinv^2 + bp. Thread per node.
// ---------------------------------------------------------------------------
__global__ void k_sconv(const float* __restrict__ sW, const float* __restrict__ dinv,
                        const int* __restrict__ row_ptr, const int* __restrict__ colI,
                        const int* __restrict__ rows, int nrows,
                        const float* __restrict__ bp, float* __restrict__ s) {
    int i = blockIdx.x * 256 + threadIdx.x;
    if (i >= nrows) return;
    int v = rows[i];
    float dv = dinv[v];
    float acc = sW[v] * dv * dv + bp[0];
    int e0 = row_ptr[v], e1 = row_ptr[v + 1];
    for (int e = e0; e < e1; ++e) {
        int u = colI[e];
        float w = dinv[u] * dv;
        if (w > 0.f) acc += w * sW[u];
    }
    s[v] = acc;
}

// ---------------------------------------------------------------------------
// Per-graph top-k: bitonic sort of 256 (value desc, index asc — matches
// jax.lax.top_k), write kept nodes to active_list, rebuild nmask.
// ---------------------------------------------------------------------------
__global__ __launch_bounds__(NPG)
void k_topk(const float* __restrict__ s, float* __restrict__ nmask,
            int* __restrict__ alist, int K) {
    const int g = blockIdx.x, t = threadIdx.x;
    __shared__ float vals[NPG];
    __shared__ int idxs[NPG];
    const int v = g * NPG + t;
    vals[t] = (nmask[v] > 0.f) ? s[v] : -__builtin_inff();
    idxs[t] = t;
    __syncthreads();
    for (int k = 2; k <= NPG; k <<= 1) {
        for (int j = k >> 1; j > 0; j >>= 1) {
            int ixj = t ^ j;
            if (ixj > t) {
                float v1 = vals[t], v2 = vals[ixj];
                int i1 = idxs[t], i2 = idxs[ixj];
                // "greater" = larger value, tie -> smaller index
                bool g12 = (v1 > v2) || (v1 == v2 && i1 < i2);
                bool desc = ((t & k) == 0);
                bool sw = desc ? (!g12) : g12;
                if (sw) {
                    vals[t] = v2; idxs[t] = i2;
                    vals[ixj] = v1; idxs[ixj] = i1;
                }
            }
            __syncthreads();
        }
    }
    nmask[v] = 0.f;
    __syncthreads();
    if (t < K) {
        int node = g * NPG + idxs[t];
        alist[g * K + t] = node;
        nmask[node] = 1.f;
    }
}

// ---------------------------------------------------------------------------
// Fused tanh-gate + readout: h[v] *= tanh(s[v]) for kept v; z[g] += [max, mean]
// One block (128 threads = feature dim) per graph.
// ---------------------------------------------------------------------------
__global__ __launch_bounds__(128)
void k_readout(float* __restrict__ h, const float* __restrict__ s,
               const int* __restrict__ alist, int K, float* __restrict__ z) {
    const int g = blockIdx.x, t = threadIdx.x;
    __shared__ float th[128];
    __shared__ int vk[128];
    if (t < K) {
        int v = alist[g * K + t];
        vk[t] = v;
        th[t] = tanhf(s[v]);
    }
    __syncthreads();
    float mx = -3.402823466e38f, sm = 0.f;
    for (int i = 0; i < K; ++i) {
        int v = vk[i];
        float val = h[(size_t)v * FD + t] * th[i];
        h[(size_t)v * FD + t] = val;
        mx = fmaxf(mx, val);
        sm += val;
    }
    z[g * 2 * FD + t] += mx;
    z[g * 2 * FD + FD + t] += sm / (float)K;
}

// ---------------------------------------------------------------------------
// Final MLP + log_softmax, one block (128 threads) per graph.
// ---------------------------------------------------------------------------
__global__ __launch_bounds__(128)
void k_mlp(const float* __restrict__ z,
           const float* __restrict__ Wl1, const float* __restrict__ bl1,
           const float* __restrict__ Wl2, const float* __restrict__ bl2,
           const float* __restrict__ Wl3, const float* __restrict__ bl3,
           float* __restrict__ out) {
    const int g = blockIdx.x, t = threadIdx.x;
    __shared__ float zr[256];
    __shared__ float h1[128];
    __shared__ float h2[64];
    __shared__ float o[NC];
    zr[t] = z[g * 256 + t];
    zr[128 + t] = z[g * 256 + 128 + t];
    __syncthreads();
    float acc = bl1[t];
#pragma unroll 8
    for (int k = 0; k < 256; ++k) acc += zr[k] * Wl1[k * 128 + t];
    h1[t] = fmaxf(acc, 0.f);
    __syncthreads();
    if (t < 64) {
        float a2 = bl2[t];
#pragma unroll 8
        for (int k = 0; k < 128; ++k) a2 += h1[k] * Wl2[k * 64 + t];
        h2[t] = fmaxf(a2, 0.f);
    }
    __syncthreads();
    if (t < NC) {
        float a3 = bl3[t];
#pragma unroll
        for (int k = 0; k < 64; ++k) a3 += h2[k] * Wl3[k * NC + t];
        o[t] = a3;
    }
    __syncthreads();
    if (t == 0) {
        float m = o[0];
        for (int c = 1; c < NC; ++c) m = fmaxf(m, o[c]);
        float se = 0.f;
        for (int c = 0; c < NC; ++c) se += expf(o[c] - m);
        float lse = m + logf(se);
        for (int c = 0; c < NC; ++c) out[g * NC + c] = o[c] - lse;
    }
}

// ---------------------------------------------------------------------------
extern "C" void kernel_launch(void* const* d_in, const int* in_sizes, int n_in,
                              void* d_out, int out_size, void* d_ws, size_t ws_size,
                              hipStream_t stream) {
    const float* x  = (const float*)d_in[0];
    const int*   ei = (const int*)d_in[1];
    const float* W[3]  = {(const float*)d_in[3], (const float*)d_in[7],  (const float*)d_in[11]};
    const float* b[3]  = {(const float*)d_in[4], (const float*)d_in[8],  (const float*)d_in[12]};
    const float* Wp[3] = {(const float*)d_in[5], (const float*)d_in[9],  (const float*)d_in[13]};
    const float* bp[3] = {(const float*)d_in[6], (const float*)d_in[10], (const float*)d_in[14]};
    const float* Wl1 = (const float*)d_in[15];
    const float* bl1 = (const float*)d_in[16];
    const float* Wl2 = (const float*)d_in[17];
    const float* bl2 = (const float*)d_in[18];
    const float* Wl3 = (const float*)d_in[19];
    const float* bl3 = (const float*)d_in[20];
    float* out = (float*)d_out;

    // Workspace layout (fp32 unless noted): ~73 MB total
    float* ws    = (float*)d_ws;
    float* hbuf  = ws;                          // NN*FD
    float* hWb   = hbuf + (size_t)NN * FD;      // NN*FD
    float* sWb   = hWb + (size_t)NN * FD;       // NN
    float* sb    = sWb + NN;                    // NN
    float* dinv  = sb + NN;                     // NN
    float* nmask = dinv + NN;                   // NN
    float* z     = nmask + NN;                  // NB*2*FD == NN
    int* row_ptr = (int*)(z + NN);              // NN+1 (+pad)
    int* colI    = row_ptr + NN + 256;          // NE
    int* alist   = colI + NE;                   // NN

    k_init<<<NN / 256, 256, 0, stream>>>(nmask, alist, z);
    k_csr<<<NB, NPG, 0, stream>>>(ei, row_ptr, colI);

    int NA = NN;
    const int Ks[3] = {128, 64, 32};
    const float* Xin = x;
    for (int L = 0; L < 3; ++L) {
        k_gemm<<<NA / 4, 128, 0, stream>>>(Xin, W[L], alist, NA, hWb);
        k_dinv<<<NN / 256, 256, 0, stream>>>(nmask, row_ptr, colI, dinv);
        k_conv<<<NA, 128, 0, stream>>>(hWb, dinv, row_ptr, colI, alist, b[L], hbuf);
        k_smatvec<<<NA / 4, 256, 0, stream>>>(hbuf, Wp[L], alist, NA, sWb);
        k_sconv<<<NA / 256, 256, 0, stream>>>(sWb, dinv, row_ptr, colI, alist, NA, bp[L], sb);
        k_topk<<<NB, NPG, 0, stream>>>(sb, nmask, alist, Ks[L]);
        NA = NB * Ks[L];
        k_readout<<<NB, 128, 0, stream>>>(hbuf, sb, alist, Ks[L], z);
        Xin = hbuf;
    }
    k_mlp<<<NB, 128, 0, stream>>>(z, Wl1, bl1, Wl2, bl2, Wl3, bl3, out);
}

// Round 2
// 358.415 us; speedup vs baseline: 1.4136x; 1.4136x over previous
//
#include <hip/hip_runtime.h>
#include <math.h>

// Problem constants (fixed by the reference)
#define NB   256                 // graphs
#define NPG  256                 // nodes per graph
#define NN   (NB * NPG)          // 65536 nodes
#define NE   (NN * 16)           // 1048576 edges
#define EPG  (NE / NB)           // 4096 edges per graph
#define FD   128                 // F == H
#define NC   10

// ---------------------------------------------------------------------------
// init: nmask = 1, active_list = iota, z = 0  (z has NB*2*FD == NN elements)
// ---------------------------------------------------------------------------
__global__ void k_init(float* __restrict__ nmask, int* __restrict__ alist,
                       float* __restrict__ z) {
    int i = blockIdx.x * 256 + threadIdx.x;
    nmask[i] = 1.f;
    alist[i] = i;
    z[i] = 0.f;
}

// ---------------------------------------------------------------------------
// CSR-by-dst build, one block per graph (edges are graph-contiguous).
// ---------------------------------------------------------------------------
__global__ __launch_bounds__(NPG)
void k_csr(const int* __restrict__ ei, int* __restrict__ row_ptr,
           int* __restrict__ colI) {
    const int g = blockIdx.x, t = threadIdx.x;
    const int* __restrict__ srcA = ei;
    const int* __restrict__ dstA = ei + NE;
    __shared__ int cnt[NPG];
    __shared__ int sc[NPG];
    __shared__ int off[NPG];
    cnt[t] = 0;
    __syncthreads();
    const int base = g * EPG;
    for (int e = t; e < EPG; e += NPG)
        atomicAdd(&cnt[dstA[base + e] - g * NPG], 1);
    __syncthreads();
    sc[t] = cnt[t];
    __syncthreads();
    for (int o = 1; o < NPG; o <<= 1) {
        int add = (t >= o) ? sc[t - o] : 0;
        __syncthreads();
        sc[t] += add;
        __syncthreads();
    }
    int excl = sc[t] - cnt[t];
    row_ptr[g * NPG + t] = base + excl;
    if (g == 0 && t == 0) row_ptr[NN] = NE;
    off[t] = excl;
    __syncthreads();
    for (int e = t; e < EPG; e += NPG) {
        int d = dstA[base + e] - g * NPG;
        int p = atomicAdd(&off[d], 1);
        colI[base + p] = srcA[base + e];
    }
}

// ---------------------------------------------------------------------------
// Row-gathered GEMM: Y[v] = X[v] @ W  for v in rows[0..nrows)
// 8 rows per 128-thread block; X rows staged in LDS (broadcast reads).
// ---------------------------------------------------------------------------
__global__ __launch_bounds__(128)
void k_gemm(const float* __restrict__ X, const float* __restrict__ W,
            const int* __restrict__ rows, int nrows, float* __restrict__ Y) {
    const int t = threadIdx.x;
    const int rb = blockIdx.x * 8;
    __shared__ float xs[8][FD];
    int vidx[8];
#pragma unroll
    for (int r = 0; r < 8; ++r) {
        int rr = rb + r;
        int v = (rr < nrows) ? rows[rr] : -1;
        vidx[r] = v;
        xs[r][t] = (v >= 0) ? X[(size_t)v * FD + t] : 0.f;
    }
    __syncthreads();
    float a[8];
#pragma unroll
    for (int r = 0; r < 8; ++r) a[r] = 0.f;
#pragma unroll 4
    for (int k = 0; k < FD; ++k) {
        float w = W[k * FD + t];
#pragma unroll
        for (int r = 0; r < 8; ++r) a[r] += xs[r][k] * w;
    }
#pragma unroll
    for (int r = 0; r < 8; ++r)
        if (vidx[r] >= 0) Y[(size_t)vidx[r] * FD + t] = a[r];
}

// ---------------------------------------------------------------------------
// dinv[v] = nmask[v] ? rsqrt(1 + sum_{in-edges} nmask[src]) : 0   (all N nodes)
// ---------------------------------------------------------------------------
__global__ void k_dinv(const float* __restrict__ nmask,
                       const int* __restrict__ row_ptr,
                       const int* __restrict__ colI, float* __restrict__ dinv) {
    int v = blockIdx.x * 256 + threadIdx.x;
    float dv = 0.f;
    if (nmask[v] > 0.f) {
        float sum = 1.f;
        int e0 = row_ptr[v], e1 = row_ptr[v + 1];
        int e = e0;
        for (; e + 8 <= e1; e += 8) {
            int u0 = colI[e],     u1 = colI[e + 1], u2 = colI[e + 2], u3 = colI[e + 3];
            int u4 = colI[e + 4], u5 = colI[e + 5], u6 = colI[e + 6], u7 = colI[e + 7];
            sum += nmask[u0] + nmask[u1] + nmask[u2] + nmask[u3]
                 + nmask[u4] + nmask[u5] + nmask[u6] + nmask[u7];
        }
        for (; e < e1; ++e) sum += nmask[colI[e]];
        dv = rsqrtf(sum);
    }
    dinv[v] = dv;
}

// ---------------------------------------------------------------------------
// Main conv finalize: h[v] = relu( sum_e w*hW[src] + hW[v]*dinv^2 + b ),
// one block (128 threads = feature dim) per active node. Unconditional
// unrolled-by-4 edge loop: w==0 annihilates inactive contributions.
// ---------------------------------------------------------------------------
__global__ __launch_bounds__(128)
void k_conv(const float* __restrict__ hW, const float* __restrict__ dinv,
            const int* __restrict__ row_ptr, const int* __restrict__ colI,
            const int* __restrict__ rows, const float* __restrict__ bias,
            float* __restrict__ outH) {
    const int v = rows[blockIdx.x];
    const int t = threadIdx.x;
    const float dv = dinv[v];
    float acc = hW[(size_t)v * FD + t] * dv * dv + bias[t];
    const int e0 = row_ptr[v], e1 = row_ptr[v + 1];
    int e = e0;
    for (; e + 4 <= e1; e += 4) {
        int u0 = colI[e], u1 = colI[e + 1], u2 = colI[e + 2], u3 = colI[e + 3];
        float w0 = dinv[u0], w1 = dinv[u1], w2 = dinv[u2], w3 = dinv[u3];
        float h0 = hW[(size_t)u0 * FD + t];
        float h1 = hW[(size_t)u1 * FD + t];
        float h2 = hW[(size_t)u2 * FD + t];
        float h3 = hW[(size_t)u3 * FD + t];
        acc += dv * (w0 * h0 + w1 * h1 + w2 * h2 + w3 * h3);
    }
    for (; e < e1; ++e) {
        int u = colI[e];
        acc += dv * dinv[u] * hW[(size_t)u * FD + t];
    }
    outH[(size_t)v * FD + t] = fmaxf(acc, 0.f);
}

// ---------------------------------------------------------------------------
// Score matvec: sW[v] = dot(h[v], Wp). One wave per node (4 waves/block).
// ---------------------------------------------------------------------------
__global__ __launch_bounds__(256)
void k_smatvec(const float* __restrict__ h, const float* __restrict__ Wp,
               const int* __restrict__ rows, int nrows, float* __restrict__ sW) {
    int wid = blockIdx.x * 4 + (threadIdx.x >> 6);
    int lane = threadIdx.x & 63;
    if (wid >= nrows) return;
    int v = rows[wid];
    float a = h[(size_t)v * FD + lane] * Wp[lane] +
              h[(size_t)v * FD + 64 + lane] * Wp[64 + lane];
#pragma unroll
    for (int o = 32; o > 0; o >>= 1) a += __shfl_xor(a, o);
    if (lane == 0) sW[v] = a;
}

// ---------------------------------------------------------------------------
// Score conv: s[v] = sum_e w*sW[src] + sW[v]*dinv^2 + bp. Thread per node.
// ---------------------------------------------------------------------------
__global__ void k_sconv(const float* __restrict__ sW, const float* __restrict__ dinv,
                        const int* __restrict__ row_ptr, const int* __restrict__ colI,
                        const int* __restrict__ rows, int nrows,
                        const float* __restrict__ bp, float* __restrict__ s) {
    int i = blockIdx.x * 256 + threadIdx.x;
    if (i >= nrows) return;
    int v = rows[i];
    float dv = dinv[v];
    float acc = sW[v] * dv * dv + bp[0];
    int e0 = row_ptr[v], e1 = row_ptr[v + 1];
    int e = e0;
    for (; e + 4 <= e1; e += 4) {
        int u0 = colI[e], u1 = colI[e + 1], u2 = colI[e + 2], u3 = colI[e + 3];
        float w0 = dinv[u0], w1 = dinv[u1], w2 = dinv[u2], w3 = dinv[u3];
        float s0 = sW[u0], s1 = sW[u1], s2 = sW[u2], s3 = sW[u3];
        acc += dv * (w0 * s0 + w1 * s1 + w2 * s2 + w3 * s3);
    }
    for (; e < e1; ++e) {
        int u = colI[e];
        acc += dv * dinv[u] * sW[u];
    }
    s[v] = acc;
}

// ---------------------------------------------------------------------------
// Per-graph top-k: bitonic sort of 256 (value desc, index asc — matches
// jax.lax.top_k), write kept nodes to active_list, rebuild nmask.
// ---------------------------------------------------------------------------
__global__ __launch_bounds__(NPG)
void k_topk(const float* __restrict__ s, float* __restrict__ nmask,
            int* __restrict__ alist, int K) {
    const int g = blockIdx.x, t = threadIdx.x;
    __shared__ float vals[NPG];
    __shared__ int idxs[NPG];
    const int v = g * NPG + t;
    vals[t] = (nmask[v] > 0.f) ? s[v] : -__builtin_inff();
    idxs[t] = t;
    __syncthreads();
    for (int k = 2; k <= NPG; k <<= 1) {
        for (int j = k >> 1; j > 0; j >>= 1) {
            int ixj = t ^ j;
            if (ixj > t) {
                float v1 = vals[t], v2 = vals[ixj];
                int i1 = idxs[t], i2 = idxs[ixj];
                bool g12 = (v1 > v2) || (v1 == v2 && i1 < i2);
                bool desc = ((t & k) == 0);
                bool sw = desc ? (!g12) : g12;
                if (sw) {
                    vals[t] = v2; idxs[t] = i2;
                    vals[ixj] = v1; idxs[ixj] = i1;
                }
            }
            __syncthreads();
        }
    }
    nmask[v] = 0.f;
    __syncthreads();
    if (t < K) {
        int node = g * NPG + idxs[t];
        alist[g * K + t] = node;
        nmask[node] = 1.f;
    }
}

// ---------------------------------------------------------------------------
// Fused tanh-gate + readout: h[v] *= tanh(s[v]) for kept v; z[g] += [max, mean]
// One block of 512 threads per graph: 4 node-slices x 128 features.
// ---------------------------------------------------------------------------
__global__ __launch_bounds__(512)
void k_readout(float* __restrict__ h, const float* __restrict__ s,
               const int* __restrict__ alist, int K, float* __restrict__ z) {
    const int g = blockIdx.x;
    const int t = threadIdx.x & 127;
    const int sl = threadIdx.x >> 7;        // 0..3
    __shared__ float th[128];
    __shared__ int vk[128];
    __shared__ float rmx[4][128];
    __shared__ float rsm[4][128];
    if (threadIdx.x < K) {
        int v = alist[g * K + threadIdx.x];
        vk[threadIdx.x] = v;
        th[threadIdx.x] = tanhf(s[v]);
    }
    __syncthreads();
    float mx = -3.402823466e38f, sm = 0.f;
    for (int i = sl; i < K; i += 4) {
        int v = vk[i];
        float val = h[(size_t)v * FD + t] * th[i];
        h[(size_t)v * FD + t] = val;
        mx = fmaxf(mx, val);
        sm += val;
    }
    rmx[sl][t] = mx;
    rsm[sl][t] = sm;
    __syncthreads();
    if (sl == 0) {
        mx = fmaxf(fmaxf(rmx[0][t], rmx[1][t]), fmaxf(rmx[2][t], rmx[3][t]));
        sm = rsm[0][t] + rsm[1][t] + rsm[2][t] + rsm[3][t];
        z[g * 2 * FD + t] += mx;
        z[g * 2 * FD + FD + t] += sm / (float)K;
    }
}

// ---------------------------------------------------------------------------
// Final MLP + log_softmax, one block (128 threads) per graph.
// ---------------------------------------------------------------------------
__global__ __launch_bounds__(128)
void k_mlp(const float* __restrict__ z,
           const float* __restrict__ Wl1, const float* __restrict__ bl1,
           const float* __restrict__ Wl2, const float* __restrict__ bl2,
           const float* __restrict__ Wl3, const float* __restrict__ bl3,
           float* __restrict__ out) {
    const int g = blockIdx.x, t = threadIdx.x;
    __shared__ float zr[256];
    __shared__ float h1[128];
    __shared__ float h2[64];
    __shared__ float o[NC];
    zr[t] = z[g * 256 + t];
    zr[128 + t] = z[g * 256 + 128 + t];
    __syncthreads();
    float acc = bl1[t];
#pragma unroll 8
    for (int k = 0; k < 256; ++k) acc += zr[k] * Wl1[k * 128 + t];
    h1[t] = fmaxf(acc, 0.f);
    __syncthreads();
    if (t < 64) {
        float a2 = bl2[t];
#pragma unroll 8
        for (int k = 0; k < 128; ++k) a2 += h1[k] * Wl2[k * 64 + t];
        h2[t] = fmaxf(a2, 0.f);
    }
    __syncthreads();
    if (t < NC) {
        float a3 = bl3[t];
#pragma unroll
        for (int k = 0; k < 64; ++k) a3 += h2[k] * Wl3[k * NC + t];
        o[t] = a3;
    }
    __syncthreads();
    if (t == 0) {
        float m = o[0];
        for (int c = 1; c < NC; ++c) m = fmaxf(m, o[c]);
        float se = 0.f;
        for (int c = 0; c < NC; ++c) se += expf(o[c] - m);
        float lse = m + logf(se);
        for (int c = 0; c < NC; ++c) out[g * NC + c] = o[c] - lse;
    }
}

// ---------------------------------------------------------------------------
extern "C" void kernel_launch(void* const* d_in, const int* in_sizes, int n_in,
                              void* d_out, int out_size, void* d_ws, size_t ws_size,
                              hipStream_t stream) {
    const float* x  = (const float*)d_in[0];
    const int*   ei = (const int*)d_in[1];
    const float* W[3]  = {(const float*)d_in[3], (const float*)d_in[7],  (const float*)d_in[11]};
    const float* b[3]  = {(const float*)d_in[4], (const float*)d_in[8],  (const float*)d_in[12]};
    const float* Wp[3] = {(const float*)d_in[5], (const float*)d_in[9],  (const float*)d_in[13]};
    const float* bp[3] = {(const float*)d_in[6], (const float*)d_in[10], (const float*)d_in[14]};
    const float* Wl1 = (const float*)d_in[15];
    const float* bl1 = (const float*)d_in[16];
    const float* Wl2 = (const float*)d_in[17];
    const float* bl2 = (const float*)d_in[18];
    const float* Wl3 = (const float*)d_in[19];
    const float* bl3 = (const float*)d_in[20];
    float* out = (float*)d_out;

    // Workspace layout (fp32 unless noted): ~73 MB total
    float* ws    = (float*)d_ws;
    float* hbuf  = ws;                          // NN*FD
    float* hWb   = hbuf + (size_t)NN * FD;      // NN*FD
    float* sWb   = hWb + (size_t)NN * FD;       // NN
    float* sb    = sWb + NN;                    // NN
    float* dinv  = sb + NN;                     // NN
    float* nmask = dinv + NN;                   // NN
    float* z     = nmask + NN;                  // NB*2*FD == NN
    int* row_ptr = (int*)(z + NN);              // NN+1 (+pad)
    int* colI    = row_ptr + NN + 256;          // NE
    int* alist   = colI + NE;                   // NN

    k_init<<<NN / 256, 256, 0, stream>>>(nmask, alist, z);
    k_csr<<<NB, NPG, 0, stream>>>(ei, row_ptr, colI);

    int NA = NN;
    const int Ks[3] = {128, 64, 32};
    const float* Xin = x;
    for (int L = 0; L < 3; ++L) {
        k_gemm<<<NA / 8, 128, 0, stream>>>(Xin, W[L], alist, NA, hWb);
        k_dinv<<<NN / 256, 256, 0, stream>>>(nmask, row_ptr, colI, dinv);
        k_conv<<<NA, 128, 0, stream>>>(hWb, dinv, row_ptr, colI, alist, b[L], hbuf);
        k_smatvec<<<NA / 4, 256, 0, stream>>>(hbuf, Wp[L], alist, NA, sWb);
        k_sconv<<<NA / 256, 256, 0, stream>>>(sWb, dinv, row_ptr, colI, alist, NA, bp[L], sb);
        k_topk<<<NB, NPG, 0, stream>>>(sb, nmask, alist, Ks[L]);
        NA = NB * Ks[L];
        k_readout<<<NB, 128 * 4, 0, stream>>>(hbuf, sb, alist, Ks[L], z);
        Xin = hbuf;
    }
    k_mlp<<<NB, 128, 0, stream>>>(z, Wl1, bl1, Wl2, bl2, Wl3, bl3, out);
}

// Round 3
// 255.619 us; speedup vs baseline: 1.9820x; 1.4021x over previous
//
#include <hip/hip_runtime.h>
#include <math.h>

// Problem constants (fixed by the reference)
#define NB   256                 // graphs
#define NPG  256                 // nodes per graph
#define NN   (NB * NPG)          // 65536 nodes
#define NE   (NN * 16)           // 1048576 edges
#define EPG  (NE / NB)           // 4096 edges per graph
#define FD   128                 // F == H
#define NC   10
#define NEG_INF (-3.402823466e38f)

// ---------------------------------------------------------------------------
// init: nmask = 1, active_list = iota, z = 0  (z has NB*2*FD == NN elements)
// ---------------------------------------------------------------------------
__global__ void k_init(float* __restrict__ nmask, int* __restrict__ alist,
                       float* __restrict__ z) {
    int i = blockIdx.x * 256 + threadIdx.x;
    nmask[i] = 1.f;
    alist[i] = i;
    z[i] = 0.f;
}

// ---------------------------------------------------------------------------
// CSR-by-dst build, one block per graph (edges are graph-contiguous).
// ---------------------------------------------------------------------------
__global__ __launch_bounds__(NPG)
void k_csr(const int* __restrict__ ei, int* __restrict__ row_ptr,
           int* __restrict__ colI) {
    const int g = blockIdx.x, t = threadIdx.x;
    const int* __restrict__ srcA = ei;
    const int* __restrict__ dstA = ei + NE;
    __shared__ int cnt[NPG];
    __shared__ int sc[NPG];
    __shared__ int off[NPG];
    cnt[t] = 0;
    __syncthreads();
    const int base = g * EPG;
    for (int e = t; e < EPG; e += NPG)
        atomicAdd(&cnt[dstA[base + e] - g * NPG], 1);
    __syncthreads();
    sc[t] = cnt[t];
    __syncthreads();
    for (int o = 1; o < NPG; o <<= 1) {
        int add = (t >= o) ? sc[t - o] : 0;
        __syncthreads();
        sc[t] += add;
        __syncthreads();
    }
    int excl = sc[t] - cnt[t];
    row_ptr[g * NPG + t] = base + excl;
    if (g == 0 && t == 0) row_ptr[NN] = NE;
    off[t] = excl;
    __syncthreads();
    for (int e = t; e < EPG; e += NPG) {
        int d = dstA[base + e] - g * NPG;
        int p = atomicAdd(&off[d], 1);
        colI[base + p] = srcA[base + e];
    }
}

// ---------------------------------------------------------------------------
// Row-gathered GEMM: Y[v] = X[v] @ W  for v in rows[0..nrows); nrows % 16 == 0.
// 16 rows per 128-thread block; X rows staged in LDS (broadcast reads).
// ---------------------------------------------------------------------------
__global__ __launch_bounds__(128)
void k_gemm(const float* __restrict__ X, const float* __restrict__ W,
            const int* __restrict__ rows, float* __restrict__ Y) {
    const int t = threadIdx.x;
    const int rb = blockIdx.x * 16;
    __shared__ float xs[16][FD];
    int vidx[16];
#pragma unroll
    for (int r = 0; r < 16; ++r) {
        int v = rows[rb + r];
        vidx[r] = v;
        xs[r][t] = X[(size_t)v * FD + t];
    }
    __syncthreads();
    float a[16];
#pragma unroll
    for (int r = 0; r < 16; ++r) a[r] = 0.f;
#pragma unroll 4
    for (int k = 0; k < FD; ++k) {
        float w = W[k * FD + t];
#pragma unroll
        for (int r = 0; r < 16; ++r) a[r] += xs[r][k] * w;
    }
#pragma unroll
    for (int r = 0; r < 16; ++r)
        Y[(size_t)vidx[r] * FD + t] = a[r];
}

// ---------------------------------------------------------------------------
// Fused per-graph level: stage hW -> LDS, dinv, conv(+relu) into registers,
// score matvec, score conv, bitonic top-k, tanh-gate + write kept rows,
// readout (max/mean) accumulated into z. One 512-thread block per graph.
// Thread layout: f4 = tid&31 (feature quad), s = tid>>5 (slice 0..15);
// slice s owns nodes v = c*16+s, c = 0..15 (hreg[c] = 4 features of node v).
// ---------------------------------------------------------------------------
__global__ __launch_bounds__(512)
void k_level(const float* __restrict__ hW, float* __restrict__ hbuf,
             float* __restrict__ nmask_g, const int* __restrict__ row_ptr,
             const int* __restrict__ colI, const float* __restrict__ bias,
             const float* __restrict__ Wp, const float* __restrict__ bp_,
             int* __restrict__ alist, int K, float* __restrict__ z) {
    __shared__ float hs[NPG][FD];          // 128 KB
    __shared__ float nm[NPG];
    __shared__ float dvv[NPG];
    __shared__ float sw[NPG];
    __shared__ float sf[NPG];
    __shared__ float svv[NPG];
    __shared__ int   si[NPG];
    __shared__ float th[NPG];
    __shared__ int   keptf[NPG];
    __shared__ float red_mx[8][FD];
    __shared__ float red_sm[8][FD];

    const int g = blockIdx.x, tid = threadIdx.x;
    const int gbase = g * NPG;
    const int f4 = tid & 31;
    const int s  = tid >> 5;

    if (tid < NPG) nm[tid] = nmask_g[gbase + tid];
    __syncthreads();

    // ---- stage active rows into LDS (zeros for inactive slots) ----
    for (int r = s; r < NPG; r += 16) {
        float4 vl = make_float4(0.f, 0.f, 0.f, 0.f);
        if (nm[r] > 0.f)
            vl = *(const float4*)&hW[((size_t)(gbase + r)) * FD + 4 * f4];
        *(float4*)&hs[r][4 * f4] = vl;
    }
    // ---- dinv (threads 0..255, one node each) ----
    if (tid < NPG) {
        float dv_ = 0.f;
        if (nm[tid] > 0.f) {
            float sum = 1.f;
            int e0 = row_ptr[gbase + tid], e1 = row_ptr[gbase + tid + 1];
            int e = e0;
            for (; e + 4 <= e1; e += 4) {
                int u0 = colI[e] - gbase, u1 = colI[e + 1] - gbase;
                int u2 = colI[e + 2] - gbase, u3 = colI[e + 3] - gbase;
                sum += nm[u0] + nm[u1] + nm[u2] + nm[u3];
            }
            for (; e < e1; ++e) sum += nm[colI[e] - gbase];
            dv_ = rsqrtf(sum);
        }
        dvv[tid] = dv_;
    }
    __syncthreads();

    // ---- conv + relu + fused score matvec ----
    const float4 wp4 = *(const float4*)&Wp[4 * f4];
    const float4 b4  = *(const float4*)&bias[4 * f4];
    const float  bp0 = bp_[0];
    float4 hreg[16];

#pragma unroll
    for (int c = 0; c < 16; ++c) {
        const int v = c * 16 + s;
        const float dv_ = dvv[v];
        const float dv2 = dv_ * dv_;
        const float4 hv = *(const float4*)&hs[v][4 * f4];
        float4 acc;
        acc.x = hv.x * dv2 + b4.x;
        acc.y = hv.y * dv2 + b4.y;
        acc.z = hv.z * dv2 + b4.z;
        acc.w = hv.w * dv2 + b4.w;
        const int e0 = row_ptr[gbase + v], e1 = row_ptr[gbase + v + 1];
        int e = e0;
        for (; e + 4 <= e1; e += 4) {
            int u0 = colI[e] - gbase, u1 = colI[e + 1] - gbase;
            int u2 = colI[e + 2] - gbase, u3 = colI[e + 3] - gbase;
            float w0 = dvv[u0] * dv_, w1 = dvv[u1] * dv_;
            float w2 = dvv[u2] * dv_, w3 = dvv[u3] * dv_;
            float4 h0 = *(const float4*)&hs[u0][4 * f4];
            float4 h1 = *(const float4*)&hs[u1][4 * f4];
            float4 h2 = *(const float4*)&hs[u2][4 * f4];
            float4 h3 = *(const float4*)&hs[u3][4 * f4];
            acc.x += w0 * h0.x + w1 * h1.x + w2 * h2.x + w3 * h3.x;
            acc.y += w0 * h0.y + w1 * h1.y + w2 * h2.y + w3 * h3.y;
            acc.z += w0 * h0.z + w1 * h1.z + w2 * h2.z + w3 * h3.z;
            acc.w += w0 * h0.w + w1 * h1.w + w2 * h2.w + w3 * h3.w;
        }
        for (; e < e1; ++e) {
            int u = colI[e] - gbase;
            float w = dvv[u] * dv_;
            float4 hu = *(const float4*)&hs[u][4 * f4];
            acc.x += w * hu.x; acc.y += w * hu.y;
            acc.z += w * hu.z; acc.w += w * hu.w;
        }
        acc.x = fmaxf(acc.x, 0.f);
        acc.y = fmaxf(acc.y, 0.f);
        acc.z = fmaxf(acc.z, 0.f);
        acc.w = fmaxf(acc.w, 0.f);
        hreg[c] = acc;
        // score partial: dot(h[v], Wp), reduced across the 32 threads (f4)
        float p = acc.x * wp4.x + acc.y * wp4.y + acc.z * wp4.z + acc.w * wp4.w;
        p += __shfl_xor(p, 1);
        p += __shfl_xor(p, 2);
        p += __shfl_xor(p, 4);
        p += __shfl_xor(p, 8);
        p += __shfl_xor(p, 16);
        if (f4 == 0) sw[v] = p;
    }
    __syncthreads();

    // ---- score conv (threads 0..255, one node each) ----
    if (tid < NPG) {
        const int v = tid;
        const float dv_ = dvv[v];
        float acc = sw[v] * dv_ * dv_ + bp0;
        const int e0 = row_ptr[gbase + v], e1 = row_ptr[gbase + v + 1];
        int e = e0;
        for (; e + 4 <= e1; e += 4) {
            int u0 = colI[e] - gbase, u1 = colI[e + 1] - gbase;
            int u2 = colI[e + 2] - gbase, u3 = colI[e + 3] - gbase;
            acc += dv_ * (dvv[u0] * sw[u0] + dvv[u1] * sw[u1] +
                          dvv[u2] * sw[u2] + dvv[u3] * sw[u3]);
        }
        for (; e < e1; ++e) {
            int u = colI[e] - gbase;
            acc += dv_ * dvv[u] * sw[u];
        }
        sf[v] = acc;
        svv[v] = (nm[v] > 0.f) ? acc : NEG_INF;
        si[v] = v;
    }
    __syncthreads();

    // ---- bitonic top-k (value desc, index asc — jax.lax.top_k semantics) ----
    for (int k = 2; k <= NPG; k <<= 1) {
        for (int j = k >> 1; j > 0; j >>= 1) {
            if (tid < NPG) {
                int ixj = tid ^ j;
                if (ixj > tid) {
                    float v1 = svv[tid], v2 = svv[ixj];
                    int i1 = si[tid], i2 = si[ixj];
                    bool g12 = (v1 > v2) || (v1 == v2 && i1 < i2);
                    bool desc = ((tid & k) == 0);
                    bool swp = desc ? (!g12) : g12;
                    if (swp) {
                        svv[tid] = v2; si[tid] = i2;
                        svv[ixj] = v1; si[ixj] = i1;
                    }
                }
            }
            __syncthreads();
        }
    }
    if (tid < NPG) keptf[tid] = 0;
    __syncthreads();
    if (tid < K) {
        int idx = si[tid];
        keptf[idx] = 1;
        th[idx] = tanhf(sf[idx]);
        alist[g * K + tid] = gbase + idx;
    }
    __syncthreads();
    if (tid < NPG) nmask_g[gbase + tid] = (float)keptf[tid];

    // ---- tanh-gate, write kept rows, readout partials ----
    float4 mx4 = make_float4(NEG_INF, NEG_INF, NEG_INF, NEG_INF);
    float4 sm4 = make_float4(0.f, 0.f, 0.f, 0.f);
#pragma unroll
    for (int c = 0; c < 16; ++c) {
        const int v = c * 16 + s;
        if (keptf[v]) {
            const float tg = th[v];
            float4 val;
            val.x = hreg[c].x * tg;
            val.y = hreg[c].y * tg;
            val.z = hreg[c].z * tg;
            val.w = hreg[c].w * tg;
            *(float4*)&hbuf[((size_t)(gbase + v)) * FD + 4 * f4] = val;
            mx4.x = fmaxf(mx4.x, val.x); sm4.x += val.x;
            mx4.y = fmaxf(mx4.y, val.y); sm4.y += val.y;
            mx4.z = fmaxf(mx4.z, val.z); sm4.z += val.z;
            mx4.w = fmaxf(mx4.w, val.w); sm4.w += val.w;
        }
    }
    // combine slice pairs within each wave (lane ^ 32)
    mx4.x = fmaxf(mx4.x, __shfl_xor(mx4.x, 32)); sm4.x += __shfl_xor(sm4.x, 32);
    mx4.y = fmaxf(mx4.y, __shfl_xor(mx4.y, 32)); sm4.y += __shfl_xor(sm4.y, 32);
    mx4.z = fmaxf(mx4.z, __shfl_xor(mx4.z, 32)); sm4.z += __shfl_xor(sm4.z, 32);
    mx4.w = fmaxf(mx4.w, __shfl_xor(mx4.w, 32)); sm4.w += __shfl_xor(sm4.w, 32);
    const int wv = tid >> 6;
    if ((tid & 63) < 32) {
        red_mx[wv][4 * f4 + 0] = mx4.x; red_sm[wv][4 * f4 + 0] = sm4.x;
        red_mx[wv][4 * f4 + 1] = mx4.y; red_sm[wv][4 * f4 + 1] = sm4.y;
        red_mx[wv][4 * f4 + 2] = mx4.z; red_sm[wv][4 * f4 + 2] = sm4.z;
        red_mx[wv][4 * f4 + 3] = mx4.w; red_sm[wv][4 * f4 + 3] = sm4.w;
    }
    __syncthreads();
    if (tid < FD) {
        float mx = NEG_INF, sm = 0.f;
#pragma unroll
        for (int i = 0; i < 8; ++i) {
            mx = fmaxf(mx, red_mx[i][tid]);
            sm += red_sm[i][tid];
        }
        z[g * 2 * FD + tid] += mx;
        z[g * 2 * FD + FD + tid] += sm / (float)K;
    }
}

// ---------------------------------------------------------------------------
// Final MLP + log_softmax, one block (128 threads) per graph.
// ---------------------------------------------------------------------------
__global__ __launch_bounds__(128)
void k_mlp(const float* __restrict__ z,
           const float* __restrict__ Wl1, const float* __restrict__ bl1,
           const float* __restrict__ Wl2, const float* __restrict__ bl2,
           const float* __restrict__ Wl3, const float* __restrict__ bl3,
           float* __restrict__ out) {
    const int g = blockIdx.x, t = threadIdx.x;
    __shared__ float zr[256];
    __shared__ float h1[128];
    __shared__ float h2[64];
    __shared__ float o[NC];
    zr[t] = z[g * 256 + t];
    zr[128 + t] = z[g * 256 + 128 + t];
    __syncthreads();
    float acc = bl1[t];
#pragma unroll 8
    for (int k = 0; k < 256; ++k) acc += zr[k] * Wl1[k * 128 + t];
    h1[t] = fmaxf(acc, 0.f);
    __syncthreads();
    if (t < 64) {
        float a2 = bl2[t];
#pragma unroll 8
        for (int k = 0; k < 128; ++k) a2 += h1[k] * Wl2[k * 64 + t];
        h2[t] = fmaxf(a2, 0.f);
    }
    __syncthreads();
    if (t < NC) {
        float a3 = bl3[t];
#pragma unroll
        for (int k = 0; k < 64; ++k) a3 += h2[k] * Wl3[k * NC + t];
        o[t] = a3;
    }
    __syncthreads();
    if (t == 0) {
        float m = o[0];
        for (int c = 1; c < NC; ++c) m = fmaxf(m, o[c]);
        float se = 0.f;
        for (int c = 0; c < NC; ++c) se += expf(o[c] - m);
        float lse = m + logf(se);
        for (int c = 0; c < NC; ++c) out[g * NC + c] = o[c] - lse;
    }
}

// ---------------------------------------------------------------------------
extern "C" void kernel_launch(void* const* d_in, const int* in_sizes, int n_in,
                              void* d_out, int out_size, void* d_ws, size_t ws_size,
                              hipStream_t stream) {
    const float* x  = (const float*)d_in[0];
    const int*   ei = (const int*)d_in[1];
    const float* W[3]  = {(const float*)d_in[3], (const float*)d_in[7],  (const float*)d_in[11]};
    const float* b[3]  = {(const float*)d_in[4], (const float*)d_in[8],  (const float*)d_in[12]};
    const float* Wp[3] = {(const float*)d_in[5], (const float*)d_in[9],  (const float*)d_in[13]};
    const float* bp[3] = {(const float*)d_in[6], (const float*)d_in[10], (const float*)d_in[14]};
    const float* Wl1 = (const float*)d_in[15];
    const float* bl1 = (const float*)d_in[16];
    const float* Wl2 = (const float*)d_in[17];
    const float* bl2 = (const float*)d_in[18];
    const float* Wl3 = (const float*)d_in[19];
    const float* bl3 = (const float*)d_in[20];
    float* out = (float*)d_out;

    // Workspace layout
    float* ws    = (float*)d_ws;
    float* hbuf  = ws;                          // NN*FD
    float* hWb   = hbuf + (size_t)NN * FD;      // NN*FD
    float* nmask = hWb + (size_t)NN * FD;       // NN
    float* z     = nmask + NN;                  // NB*2*FD == NN
    int* row_ptr = (int*)(z + NN);              // NN+1 (+pad)
    int* colI    = row_ptr + NN + 256;          // NE
    int* alist   = colI + NE;                   // NN

    k_init<<<NN / 256, 256, 0, stream>>>(nmask, alist, z);
    k_csr<<<NB, NPG, 0, stream>>>(ei, row_ptr, colI);

    int NA = NN;
    const int Ks[3] = {128, 64, 32};
    const float* Xin = x;
    for (int L = 0; L < 3; ++L) {
        k_gemm<<<NA / 16, 128, 0, stream>>>(Xin, W[L], alist, hWb);
        k_level<<<NB, 512, 0, stream>>>(hWb, hbuf, nmask, row_ptr, colI,
                                        b[L], Wp[L], bp[L], alist, Ks[L], z);
        NA = NB * Ks[L];
        Xin = hbuf;
    }
    k_mlp<<<NB, 128, 0, stream>>>(z, Wl1, bl1, Wl2, bl2, Wl3, bl3, out);
}

// Round 4
// 199.385 us; speedup vs baseline: 2.5410x; 1.2820x over previous
//
#include <hip/hip_runtime.h>
#include <math.h>

// Problem constants (fixed by the reference)
#define NB   256                 // graphs
#define NPG  256                 // nodes per graph
#define NN   (NB * NPG)          // 65536 nodes
#define NE   (NN * 16)           // 1048576 edges
#define EPG  (NE / NB)           // 4096 edges per graph
#define FD   128                 // F == H
#define NC   10
#define NSL  32                  // slices (1024 threads / 32 lanes-per-slice)
#define NEG_INF (-3.402823466e38f)

// Shared-memory layout for the fused per-graph block: 158,736 B <= 160 KiB.
struct SM {
    float hs[NPG][FD];          // 128 KB: x -> hW -> gated h (in place across levels)
    int   rp[NPG + 4];          // local CSR row pointers
    float nmloc[NPG];           // node mask
    float dvv[NPG];             // dinv
    float sw[NPG];              // score matvec result
    float sf[NPG];              // score conv result
    float svv[NPG];             // bitonic values  (also MLP logits buffer)
    float th[NPG];              // tanh(score) for kept
    float zacc[2 * FD];         // readout accumulator across levels
    int   si[NPG];              // bitonic indices (also CSR counts)
    int   kept[NPG];            // kept flags     (also CSR scatter cursor)
    int   anode[NPG];           // active list    (also CSR scan buffer)
    float red_mx[16][FD];       // per-wave readout partials
    float red_sm[16][FD];
};

// ---------------------------------------------------------------------------
// One pooling level, fully in-LDS. NACT = active node count (256/128/64).
// Thread layout: f4 = tid&31 (feature quad), s = tid>>5 (slice 0..31);
// slice s owns active indices i = c*32+s, c < NPS = NACT/32.
// ---------------------------------------------------------------------------
template <int NACT>
__device__ __forceinline__ void do_level(SM& sm, const int* __restrict__ colI_l,
                                         const float* __restrict__ Wmat,
                                         const float* __restrict__ bias,
                                         const float* __restrict__ Wp,
                                         const float* __restrict__ bpp,
                                         int K, int tid) {
    constexpr int NPS = NACT / NSL;
    const int f4 = tid & 31;
    const int s  = tid >> 5;

    // ---- dinv (waves 0..3) -- other waves proceed straight into GEMM ----
    if (tid < NPG) {
        float dv_ = 0.f;
        if (sm.nmloc[tid] > 0.f) {
            float sum = 1.f;
            const int e0 = sm.rp[tid], e1 = sm.rp[tid + 1];
            for (int e = e0; e < e1; ++e) sum += sm.nmloc[colI_l[e]];
            dv_ = rsqrtf(sum);
        }
        sm.dvv[tid] = dv_;
    }

    // ---- in-place GEMM on active rows: hs[v] <- hs[v] @ W ----
    // Row v is read and written only by the 32 lanes of the half-wave that
    // owns it (lockstep) -> no barrier needed around the in-place update.
    {
        int vr[NPS];
        float4 acc[NPS];
#pragma unroll
        for (int c = 0; c < NPS; ++c) {
            vr[c] = sm.anode[c * NSL + s];
            acc[c] = make_float4(0.f, 0.f, 0.f, 0.f);
        }
        for (int k0 = 0; k0 < FD; k0 += 4) {
            float4 w0 = *(const float4*)&Wmat[(k0 + 0) * FD + 4 * f4];
            float4 w1 = *(const float4*)&Wmat[(k0 + 1) * FD + 4 * f4];
            float4 w2 = *(const float4*)&Wmat[(k0 + 2) * FD + 4 * f4];
            float4 w3 = *(const float4*)&Wmat[(k0 + 3) * FD + 4 * f4];
#pragma unroll
            for (int c = 0; c < NPS; ++c) {
                float4 hv = *(const float4*)&sm.hs[vr[c]][k0];
                acc[c].x += hv.x * w0.x + hv.y * w1.x + hv.z * w2.x + hv.w * w3.x;
                acc[c].y += hv.x * w0.y + hv.y * w1.y + hv.z * w2.y + hv.w * w3.y;
                acc[c].z += hv.x * w0.z + hv.y * w1.z + hv.z * w2.z + hv.w * w3.z;
                acc[c].w += hv.x * w0.w + hv.y * w1.w + hv.z * w2.w + hv.w * w3.w;
            }
        }
#pragma unroll
        for (int c = 0; c < NPS; ++c)
            *(float4*)&sm.hs[vr[c]][4 * f4] = acc[c];
    }
    __syncthreads();

    // ---- conv + relu + fused score matvec (active nodes only) ----
    const float4 b4  = *(const float4*)&bias[4 * f4];
    const float4 wp4 = *(const float4*)&Wp[4 * f4];
    float4 hreg[NPS];
#pragma unroll
    for (int c = 0; c < NPS; ++c) {
        const int v = sm.anode[c * NSL + s];
        const float dv_ = sm.dvv[v], dv2 = dv_ * dv_;
        const float4 hv = *(const float4*)&sm.hs[v][4 * f4];
        float4 acc;
        acc.x = hv.x * dv2 + b4.x;
        acc.y = hv.y * dv2 + b4.y;
        acc.z = hv.z * dv2 + b4.z;
        acc.w = hv.w * dv2 + b4.w;
        const int e0 = sm.rp[v], e1 = sm.rp[v + 1];
        int e = e0;
        for (; e + 4 <= e1; e += 4) {
            int u0 = colI_l[e], u1 = colI_l[e + 1];
            int u2 = colI_l[e + 2], u3 = colI_l[e + 3];
            float w0 = sm.dvv[u0] * dv_, w1 = sm.dvv[u1] * dv_;
            float w2 = sm.dvv[u2] * dv_, w3 = sm.dvv[u3] * dv_;
            float4 h0 = *(const float4*)&sm.hs[u0][4 * f4];
            float4 h1 = *(const float4*)&sm.hs[u1][4 * f4];
            float4 h2 = *(const float4*)&sm.hs[u2][4 * f4];
            float4 h3 = *(const float4*)&sm.hs[u3][4 * f4];
            acc.x += w0 * h0.x + w1 * h1.x + w2 * h2.x + w3 * h3.x;
            acc.y += w0 * h0.y + w1 * h1.y + w2 * h2.y + w3 * h3.y;
            acc.z += w0 * h0.z + w1 * h1.z + w2 * h2.z + w3 * h3.z;
            acc.w += w0 * h0.w + w1 * h1.w + w2 * h2.w + w3 * h3.w;
        }
        for (; e < e1; ++e) {
            int u = colI_l[e];
            float w = sm.dvv[u] * dv_;
            float4 hu = *(const float4*)&sm.hs[u][4 * f4];
            acc.x += w * hu.x; acc.y += w * hu.y;
            acc.z += w * hu.z; acc.w += w * hu.w;
        }
        acc.x = fmaxf(acc.x, 0.f);
        acc.y = fmaxf(acc.y, 0.f);
        acc.z = fmaxf(acc.z, 0.f);
        acc.w = fmaxf(acc.w, 0.f);
        hreg[c] = acc;
        // score partial: dot(h[v], Wp) reduced across the 32 f4 lanes
        float p = acc.x * wp4.x + acc.y * wp4.y + acc.z * wp4.z + acc.w * wp4.w;
        p += __shfl_xor(p, 1);
        p += __shfl_xor(p, 2);
        p += __shfl_xor(p, 4);
        p += __shfl_xor(p, 8);
        p += __shfl_xor(p, 16);
        if (f4 == 0) sm.sw[v] = p;
    }
    __syncthreads();

    // ---- score conv (active nodes only) ----
    if (tid < NPG) { sm.svv[tid] = NEG_INF; sm.si[tid] = tid; }
    __syncthreads();
    if (tid < NACT) {
        const int v = sm.anode[tid];
        const float dv_ = sm.dvv[v];
        float acc = sm.sw[v] * dv_ * dv_ + bpp[0];
        const int e0 = sm.rp[v], e1 = sm.rp[v + 1];
        int e = e0;
        for (; e + 4 <= e1; e += 4) {
            int u0 = colI_l[e], u1 = colI_l[e + 1];
            int u2 = colI_l[e + 2], u3 = colI_l[e + 3];
            acc += dv_ * (sm.dvv[u0] * sm.sw[u0] + sm.dvv[u1] * sm.sw[u1] +
                          sm.dvv[u2] * sm.sw[u2] + sm.dvv[u3] * sm.sw[u3]);
        }
        for (; e < e1; ++e) {
            int u = colI_l[e];
            acc += dv_ * sm.dvv[u] * sm.sw[u];
        }
        sm.sf[v] = acc;
        sm.svv[v] = acc;
    }
    __syncthreads();

    // ---- bitonic top-k (value desc, index asc = jax.lax.top_k) ----
    for (int k = 2; k <= NPG; k <<= 1) {
        for (int j = k >> 1; j > 0; j >>= 1) {
            if (tid < NPG) {
                int ixj = tid ^ j;
                if (ixj > tid) {
                    float v1 = sm.svv[tid], v2 = sm.svv[ixj];
                    int i1 = sm.si[tid], i2 = sm.si[ixj];
                    bool g12 = (v1 > v2) || (v1 == v2 && i1 < i2);
                    bool desc = ((tid & k) == 0);
                    bool swp = desc ? (!g12) : g12;
                    if (swp) {
                        sm.svv[tid] = v2; sm.si[tid] = i2;
                        sm.svv[ixj] = v1; sm.si[ixj] = i1;
                    }
                }
            }
            __syncthreads();
        }
    }
    if (tid < NPG) sm.kept[tid] = 0;
    __syncthreads();
    if (tid < K) {
        int idx = sm.si[tid];
        sm.kept[idx] = 1;
        sm.th[idx] = tanhf(sm.sf[idx]);
    }
    __syncthreads();

    // ---- tanh-gate: write kept rows back into hs; readout partials ----
    float4 mx4 = make_float4(NEG_INF, NEG_INF, NEG_INF, NEG_INF);
    float4 sm4 = make_float4(0.f, 0.f, 0.f, 0.f);
#pragma unroll
    for (int c = 0; c < NPS; ++c) {
        const int v = sm.anode[c * NSL + s];
        if (sm.kept[v]) {
            const float tg = sm.th[v];
            float4 val;
            val.x = hreg[c].x * tg;
            val.y = hreg[c].y * tg;
            val.z = hreg[c].z * tg;
            val.w = hreg[c].w * tg;
            *(float4*)&sm.hs[v][4 * f4] = val;
            mx4.x = fmaxf(mx4.x, val.x); sm4.x += val.x;
            mx4.y = fmaxf(mx4.y, val.y); sm4.y += val.y;
            mx4.z = fmaxf(mx4.z, val.z); sm4.z += val.z;
            mx4.w = fmaxf(mx4.w, val.w); sm4.w += val.w;
        }
    }
    mx4.x = fmaxf(mx4.x, __shfl_xor(mx4.x, 32)); sm4.x += __shfl_xor(sm4.x, 32);
    mx4.y = fmaxf(mx4.y, __shfl_xor(mx4.y, 32)); sm4.y += __shfl_xor(sm4.y, 32);
    mx4.z = fmaxf(mx4.z, __shfl_xor(mx4.z, 32)); sm4.z += __shfl_xor(sm4.z, 32);
    mx4.w = fmaxf(mx4.w, __shfl_xor(mx4.w, 32)); sm4.w += __shfl_xor(sm4.w, 32);
    const int wv = tid >> 6;
    if ((tid & 63) < 32) {
        sm.red_mx[wv][4 * f4 + 0] = mx4.x; sm.red_sm[wv][4 * f4 + 0] = sm4.x;
        sm.red_mx[wv][4 * f4 + 1] = mx4.y; sm.red_sm[wv][4 * f4 + 1] = sm4.y;
        sm.red_mx[wv][4 * f4 + 2] = mx4.z; sm.red_sm[wv][4 * f4 + 2] = sm4.z;
        sm.red_mx[wv][4 * f4 + 3] = mx4.w; sm.red_sm[wv][4 * f4 + 3] = sm4.w;
    }
    __syncthreads();
    if (tid < FD) {
        float mx = NEG_INF, smv = 0.f;
#pragma unroll
        for (int i = 0; i < 16; ++i) {
            mx = fmaxf(mx, sm.red_mx[i][tid]);
            smv += sm.red_sm[i][tid];
        }
        sm.zacc[tid] += mx;
        sm.zacc[FD + tid] += smv / (float)K;
    }
    // ---- update active set for next level ----
    if (tid < NPG) sm.nmloc[tid] = (float)sm.kept[tid];
    if (tid < K) sm.anode[tid] = sm.si[tid];
    __syncthreads();
}

// ---------------------------------------------------------------------------
// Fully-fused kernel: one 1024-thread block per graph does CSR build, all
// 3 GCN+pool levels, readout, and the final MLP + log_softmax.
// ---------------------------------------------------------------------------
__global__ __launch_bounds__(1024)
void k_mega(const float* __restrict__ x, const int* __restrict__ ei,
            int* __restrict__ colI_g,
            const float* __restrict__ W1, const float* __restrict__ b1,
            const float* __restrict__ Wp1, const float* __restrict__ bp1,
            const float* __restrict__ W2, const float* __restrict__ b2,
            const float* __restrict__ Wp2, const float* __restrict__ bp2,
            const float* __restrict__ W3, const float* __restrict__ b3,
            const float* __restrict__ Wp3, const float* __restrict__ bp3,
            const float* __restrict__ Wl1, const float* __restrict__ bl1,
            const float* __restrict__ Wl2, const float* __restrict__ bl2,
            const float* __restrict__ Wl3, const float* __restrict__ bl3,
            float* __restrict__ out) {
    __shared__ SM sm;
    const int g = blockIdx.x, tid = threadIdx.x;
    const int gbase = g * NPG, ebase = g * EPG;
    const int* __restrict__ srcA = ei;
    const int* __restrict__ dstA = ei + NE;
    int* __restrict__ colI_l = colI_g + ebase;

    // ---- CSR-by-dst build (si = counts, anode = scan, kept = cursor) ----
    if (tid < NPG) sm.si[tid] = 0;
    __syncthreads();
    for (int e = tid; e < EPG; e += 1024)
        atomicAdd(&sm.si[dstA[ebase + e] - gbase], 1);
    __syncthreads();
    if (tid < NPG) sm.anode[tid] = sm.si[tid];
    __syncthreads();
    for (int o = 1; o < NPG; o <<= 1) {
        int add = 0;
        if (tid < NPG && tid >= o) add = sm.anode[tid - o];
        __syncthreads();
        if (tid < NPG) sm.anode[tid] += add;
        __syncthreads();
    }
    if (tid < NPG) {
        int excl = sm.anode[tid] - sm.si[tid];
        sm.rp[tid] = excl;
        sm.kept[tid] = excl;
        if (tid == 0) sm.rp[NPG] = EPG;
    }
    __syncthreads();
    for (int e = tid; e < EPG; e += 1024) {
        int d = dstA[ebase + e] - gbase;
        int p = atomicAdd(&sm.kept[d], 1);
        colI_l[p] = srcA[ebase + e] - gbase;       // store LOCAL src id
    }

    // ---- stage x -> LDS; init active set and readout accumulator ----
    {
        const int r0 = tid >> 5, f4 = tid & 31;
        for (int r = r0; r < NPG; r += NSL)
            *(float4*)&sm.hs[r][4 * f4] =
                *(const float4*)&x[((size_t)(gbase + r)) * FD + 4 * f4];
    }
    if (tid < NPG) { sm.anode[tid] = tid; sm.nmloc[tid] = 1.f; }
    if (tid < 2 * FD) sm.zacc[tid] = 0.f;
    __syncthreads();   // also makes colI_l writes visible block-wide

    do_level<256>(sm, colI_l, W1, b1, Wp1, bp1, 128, tid);
    do_level<128>(sm, colI_l, W2, b2, Wp2, bp2, 64, tid);
    do_level<64>(sm, colI_l, W3, b3, Wp3, bp3, 32, tid);

    // ---- final MLP + log_softmax (reuse sw/sf/svv as h1/h2/logits) ----
    if (tid < 128) {
        float a = bl1[tid];
#pragma unroll 8
        for (int k = 0; k < 256; ++k) a += sm.zacc[k] * Wl1[k * 128 + tid];
        sm.sw[tid] = fmaxf(a, 0.f);
    }
    __syncthreads();
    if (tid < 64) {
        float a = bl2[tid];
#pragma unroll 8
        for (int k = 0; k < 128; ++k) a += sm.sw[k] * Wl2[k * 64 + tid];
        sm.sf[tid] = fmaxf(a, 0.f);
    }
    __syncthreads();
    if (tid < NC) {
        float a = bl3[tid];
#pragma unroll
        for (int k = 0; k < 64; ++k) a += sm.sf[k] * Wl3[k * NC + tid];
        sm.svv[tid] = a;
    }
    __syncthreads();
    if (tid == 0) {
        float m = sm.svv[0];
        for (int c = 1; c < NC; ++c) m = fmaxf(m, sm.svv[c]);
        float se = 0.f;
        for (int c = 0; c < NC; ++c) se += expf(sm.svv[c] - m);
        float lse = m + logf(se);
        for (int c = 0; c < NC; ++c) out[g * NC + c] = sm.svv[c] - lse;
    }
}

// ---------------------------------------------------------------------------
extern "C" void kernel_launch(void* const* d_in, const int* in_sizes, int n_in,
                              void* d_out, int out_size, void* d_ws, size_t ws_size,
                              hipStream_t stream) {
    const float* x   = (const float*)d_in[0];
    const int*   ei  = (const int*)d_in[1];
    const float* W1  = (const float*)d_in[3];
    const float* b1  = (const float*)d_in[4];
    const float* Wp1 = (const float*)d_in[5];
    const float* bp1 = (const float*)d_in[6];
    const float* W2  = (const float*)d_in[7];
    const float* b2  = (const float*)d_in[8];
    const float* Wp2 = (const float*)d_in[9];
    const float* bp2 = (const float*)d_in[10];
    const float* W3  = (const float*)d_in[11];
    const float* b3  = (const float*)d_in[12];
    const float* Wp3 = (const float*)d_in[13];
    const float* bp3 = (const float*)d_in[14];
    const float* Wl1 = (const float*)d_in[15];
    const float* bl1 = (const float*)d_in[16];
    const float* Wl2 = (const float*)d_in[17];
    const float* bl2 = (const float*)d_in[18];
    const float* Wl3 = (const float*)d_in[19];
    const float* bl3 = (const float*)d_in[20];
    float* out = (float*)d_out;

    int* colI = (int*)d_ws;   // NE ints of scratch (4 MB)

    k_mega<<<NB, 1024, 0, stream>>>(x, ei, colI,
                                    W1, b1, Wp1, bp1,
                                    W2, b2, Wp2, bp2,
                                    W3, b3, Wp3, bp3,
                                    Wl1, bl1, Wl2, bl2, Wl3, bl3, out);
}

// Round 5
// 165.481 us; speedup vs baseline: 3.0616x; 1.2049x over previous
//
#include <hip/hip_runtime.h>
#include <math.h>

// Problem constants (fixed by the reference)
#define NB   256                 // graphs
#define NPG  256                 // nodes per graph
#define NN   (NB * NPG)          // 65536 nodes
#define NE   (NN * 16)           // 1048576 edges
#define EPG  (NE / NB)           // 4096 edges per graph
#define FD   128                 // F == H
#define NC   10
#define NSL  32                  // slices (1024 threads / 32 lanes-per-slice)
#define NEG_INF (-3.402823466e38f)

// Shared-memory layout for the fused per-graph block: 161,808 B <= 160 KiB.
struct SM {
    float hs[NPG][FD];          // 128 KB: x -> hW -> gated h (in place across levels)
    int   rp[NPG + 4];          // local CSR row pointers
    float nmloc[NPG];           // node mask
    float dvv[NPG];             // dinv
    float sw[NPG];              // score matvec result
    float sf[NPG];              // score conv result (by node id)
    float svv[NPG];             // sort staging / MLP logits buffer
    float th[NPG];              // tanh(score) for kept
    float zacc[2 * FD];         // readout accumulator across levels
    int   si[NPG];              // sort staging / CSR counts
    int   kept[NPG];            // kept flags / CSR scatter cursor
    int   anode[NPG];           // active list / CSR scan buffer
    float red_mx[16][FD];       // per-wave readout partials
    float red_sm[16][FD];
    unsigned char colb[EPG];    // edge src local ids (CSR-by-dst order), 4 KB
};

// ---------------------------------------------------------------------------
// One pooling level, fully in-LDS. NACT = active node count (256/128/64).
// Thread layout: f4 = tid&31 (feature quad), s = tid>>5 (slice 0..31);
// slice s owns active indices i = c*32+s, c < NPS = NACT/32.
// ---------------------------------------------------------------------------
template <int NACT>
__device__ __forceinline__ void do_level(SM& sm,
                                         const float* __restrict__ Wmat,
                                         const float* __restrict__ bias,
                                         const float* __restrict__ Wp,
                                         const float* __restrict__ bpp,
                                         int tid) {
    constexpr int NPS = NACT / NSL;
    constexpr int K   = NACT / 2;
    const int f4 = tid & 31;
    const int s  = tid >> 5;

    // ---- dinv: 4 threads per node (all 1024 threads active) ----
    {
        const int n = tid >> 2, sub = tid & 3;
        float part = 0.f;
        const float nmn = sm.nmloc[n];
        if (nmn > 0.f) {
            const int e1 = sm.rp[n + 1];
            for (int e = sm.rp[n] + sub; e < e1; e += 4)
                part += sm.nmloc[sm.colb[e]];
        }
        part += __shfl_xor(part, 1);
        part += __shfl_xor(part, 2);
        if (sub == 0)
            sm.dvv[n] = (nmn > 0.f) ? rsqrtf(1.f + part) : 0.f;
    }

    // ---- in-place GEMM on active rows: hs[v] <- hs[v] @ W ----
    // Row v is read and written only by the 32 lanes of the half-wave that
    // owns it (lockstep) -> no barrier needed around the in-place update.
    {
        int vr[NPS];
        float4 acc[NPS];
#pragma unroll
        for (int c = 0; c < NPS; ++c) {
            vr[c] = sm.anode[c * NSL + s];
            acc[c] = make_float4(0.f, 0.f, 0.f, 0.f);
        }
#pragma unroll 2
        for (int k0 = 0; k0 < FD; k0 += 4) {
            float4 w0 = *(const float4*)&Wmat[(k0 + 0) * FD + 4 * f4];
            float4 w1 = *(const float4*)&Wmat[(k0 + 1) * FD + 4 * f4];
            float4 w2 = *(const float4*)&Wmat[(k0 + 2) * FD + 4 * f4];
            float4 w3 = *(const float4*)&Wmat[(k0 + 3) * FD + 4 * f4];
#pragma unroll
            for (int c = 0; c < NPS; ++c) {
                float4 hv = *(const float4*)&sm.hs[vr[c]][k0];
                acc[c].x += hv.x * w0.x + hv.y * w1.x + hv.z * w2.x + hv.w * w3.x;
                acc[c].y += hv.x * w0.y + hv.y * w1.y + hv.z * w2.y + hv.w * w3.y;
                acc[c].z += hv.x * w0.z + hv.y * w1.z + hv.z * w2.z + hv.w * w3.z;
                acc[c].w += hv.x * w0.w + hv.y * w1.w + hv.z * w2.w + hv.w * w3.w;
            }
        }
#pragma unroll
        for (int c = 0; c < NPS; ++c)
            *(float4*)&sm.hs[vr[c]][4 * f4] = acc[c];
    }
    __syncthreads();   // publishes GEMM rows + dvv

    // ---- conv + relu + fused score matvec (active nodes only) ----
    const float4 b4  = *(const float4*)&bias[4 * f4];
    const float4 wp4 = *(const float4*)&Wp[4 * f4];
    float4 hreg[NPS];
#pragma unroll
    for (int c = 0; c < NPS; ++c) {
        const int v = sm.anode[c * NSL + s];
        const float dv_ = sm.dvv[v], dv2 = dv_ * dv_;
        const float4 hv = *(const float4*)&sm.hs[v][4 * f4];
        float4 acc;
        acc.x = hv.x * dv2 + b4.x;
        acc.y = hv.y * dv2 + b4.y;
        acc.z = hv.z * dv2 + b4.z;
        acc.w = hv.w * dv2 + b4.w;
        const int e0 = sm.rp[v], e1 = sm.rp[v + 1];
        int e = e0;
        for (; e + 4 <= e1; e += 4) {
            int u0 = sm.colb[e],     u1 = sm.colb[e + 1];
            int u2 = sm.colb[e + 2], u3 = sm.colb[e + 3];
            float w0 = sm.dvv[u0] * dv_, w1 = sm.dvv[u1] * dv_;
            float w2 = sm.dvv[u2] * dv_, w3 = sm.dvv[u3] * dv_;
            float4 h0 = *(const float4*)&sm.hs[u0][4 * f4];
            float4 h1 = *(const float4*)&sm.hs[u1][4 * f4];
            float4 h2 = *(const float4*)&sm.hs[u2][4 * f4];
            float4 h3 = *(const float4*)&sm.hs[u3][4 * f4];
            acc.x += w0 * h0.x + w1 * h1.x + w2 * h2.x + w3 * h3.x;
            acc.y += w0 * h0.y + w1 * h1.y + w2 * h2.y + w3 * h3.y;
            acc.z += w0 * h0.z + w1 * h1.z + w2 * h2.z + w3 * h3.z;
            acc.w += w0 * h0.w + w1 * h1.w + w2 * h2.w + w3 * h3.w;
        }
        for (; e < e1; ++e) {
            int u = sm.colb[e];
            float w = sm.dvv[u] * dv_;
            float4 hu = *(const float4*)&sm.hs[u][4 * f4];
            acc.x += w * hu.x; acc.y += w * hu.y;
            acc.z += w * hu.z; acc.w += w * hu.w;
        }
        acc.x = fmaxf(acc.x, 0.f);
        acc.y = fmaxf(acc.y, 0.f);
        acc.z = fmaxf(acc.z, 0.f);
        acc.w = fmaxf(acc.w, 0.f);
        hreg[c] = acc;
        // score partial: dot(h[v], Wp) reduced across the 32 f4 lanes
        float p = acc.x * wp4.x + acc.y * wp4.y + acc.z * wp4.z + acc.w * wp4.w;
        p += __shfl_xor(p, 1);
        p += __shfl_xor(p, 2);
        p += __shfl_xor(p, 4);
        p += __shfl_xor(p, 8);
        p += __shfl_xor(p, 16);
        if (f4 == 0) sm.sw[v] = p;
    }
    __syncthreads();

    // ---- score conv: 4 threads per active node ----
    {
        const int i = tid >> 2, sub = tid & 3;
        if (i < NACT) {
            const int v = sm.anode[i];
            const float dv_ = sm.dvv[v];
            float part = 0.f;
            const int e1 = sm.rp[v + 1];
            for (int e = sm.rp[v] + sub; e < e1; e += 4) {
                int u = sm.colb[e];
                part += sm.dvv[u] * sm.sw[u];
            }
            part += __shfl_xor(part, 1);
            part += __shfl_xor(part, 2);
            if (sub == 0) {
                float acc = sm.sw[v] * dv_ * dv_ + bpp[0] + dv_ * part;
                sm.sf[v] = acc;        // by node id (for tanh later)
                sm.svv[i] = acc;       // by active index (for sort)
            }
        }
    }
    __syncthreads();

    // ---- bitonic sort of NACT active elements, registers + shuffles ----
    // comparator: value desc, node-id asc  (= jax.lax.top_k semantics;
    // inactive nodes are -inf so top-K always come from actives)
    float v_ = 0.f;
    int   id_ = 0;
    if (tid < NACT) { v_ = sm.svv[tid]; id_ = sm.anode[tid]; }
#pragma unroll
    for (int k = 2; k <= NACT; k <<= 1) {
#pragma unroll
        for (int j = k >> 1; j > 0; j >>= 1) {
            if (j < 64) {
                if (tid < NACT) {
                    float vp = __shfl_xor(v_, j);
                    int  idp = __shfl_xor(id_, j);
                    bool up    = ((tid & k) == 0);
                    bool lower = ((tid & j) == 0);
                    bool g = (v_ > vp) || (v_ == vp && id_ < idp);
                    if (g != (lower == up)) { v_ = vp; id_ = idp; }
                }
            } else {
                if (tid < NACT) { sm.svv[tid] = v_; sm.si[tid] = id_; }
                __syncthreads();
                if (tid < NACT) {
                    int p = tid ^ j;
                    float vp = sm.svv[p];
                    int  idp = sm.si[p];
                    bool up    = ((tid & k) == 0);
                    bool lower = ((tid & j) == 0);
                    bool g = (v_ > vp) || (v_ == vp && id_ < idp);
                    if (g != (lower == up)) { v_ = vp; id_ = idp; }
                }
                __syncthreads();
            }
        }
    }
    if (tid < NPG) sm.kept[tid] = 0;
    __syncthreads();
    if (tid < K) {
        sm.kept[id_] = 1;
        sm.th[id_] = tanhf(sm.sf[id_]);
    }
    __syncthreads();

    // ---- tanh-gate: write kept rows back into hs; readout partials ----
    float4 mx4 = make_float4(NEG_INF, NEG_INF, NEG_INF, NEG_INF);
    float4 sm4 = make_float4(0.f, 0.f, 0.f, 0.f);
#pragma unroll
    for (int c = 0; c < NPS; ++c) {
        const int v = sm.anode[c * NSL + s];
        if (sm.kept[v]) {
            const float tg = sm.th[v];
            float4 val;
            val.x = hreg[c].x * tg;
            val.y = hreg[c].y * tg;
            val.z = hreg[c].z * tg;
            val.w = hreg[c].w * tg;
            *(float4*)&sm.hs[v][4 * f4] = val;
            mx4.x = fmaxf(mx4.x, val.x); sm4.x += val.x;
            mx4.y = fmaxf(mx4.y, val.y); sm4.y += val.y;
            mx4.z = fmaxf(mx4.z, val.z); sm4.z += val.z;
            mx4.w = fmaxf(mx4.w, val.w); sm4.w += val.w;
        }
    }
    mx4.x = fmaxf(mx4.x, __shfl_xor(mx4.x, 32)); sm4.x += __shfl_xor(sm4.x, 32);
    mx4.y = fmaxf(mx4.y, __shfl_xor(mx4.y, 32)); sm4.y += __shfl_xor(sm4.y, 32);
    mx4.z = fmaxf(mx4.z, __shfl_xor(mx4.z, 32)); sm4.z += __shfl_xor(sm4.z, 32);
    mx4.w = fmaxf(mx4.w, __shfl_xor(mx4.w, 32)); sm4.w += __shfl_xor(sm4.w, 32);
    const int wv = tid >> 6;
    if ((tid & 63) < 32) {
        sm.red_mx[wv][4 * f4 + 0] = mx4.x; sm.red_sm[wv][4 * f4 + 0] = sm4.x;
        sm.red_mx[wv][4 * f4 + 1] = mx4.y; sm.red_sm[wv][4 * f4 + 1] = sm4.y;
        sm.red_mx[wv][4 * f4 + 2] = mx4.z; sm.red_sm[wv][4 * f4 + 2] = sm4.z;
        sm.red_mx[wv][4 * f4 + 3] = mx4.w; sm.red_sm[wv][4 * f4 + 3] = sm4.w;
    }
    __syncthreads();   // all threads done with gate loop + red writes
    if (tid < FD) {
        float mx = NEG_INF, smv = 0.f;
#pragma unroll
        for (int i = 0; i < 16; ++i) {
            mx = fmaxf(mx, sm.red_mx[i][tid]);
            smv += sm.red_sm[i][tid];
        }
        sm.zacc[tid] += mx;
        sm.zacc[FD + tid] += smv / (float)K;
    }
    // ---- update active set for next level ----
    if (tid < NPG) sm.nmloc[tid] = (float)sm.kept[tid];
    if (tid < K) sm.anode[tid] = id_;
    __syncthreads();
}

// ---------------------------------------------------------------------------
// Fully-fused kernel: one 1024-thread block per graph does CSR build, all
// 3 GCN+pool levels, readout, and the final MLP + log_softmax.
// ---------------------------------------------------------------------------
__global__ __launch_bounds__(1024)
void k_mega(const float* __restrict__ x, const int* __restrict__ ei,
            const float* __restrict__ W1, const float* __restrict__ b1,
            const float* __restrict__ Wp1, const float* __restrict__ bp1,
            const float* __restrict__ W2, const float* __restrict__ b2,
            const float* __restrict__ Wp2, const float* __restrict__ bp2,
            const float* __restrict__ W3, const float* __restrict__ b3,
            const float* __restrict__ Wp3, const float* __restrict__ bp3,
            const float* __restrict__ Wl1, const float* __restrict__ bl1,
            const float* __restrict__ Wl2, const float* __restrict__ bl2,
            const float* __restrict__ Wl3, const float* __restrict__ bl3,
            float* __restrict__ out) {
    __shared__ SM sm;
    const int g = blockIdx.x, tid = threadIdx.x;
    const int gbase = g * NPG, ebase = g * EPG;
    const int* __restrict__ srcA = ei;
    const int* __restrict__ dstA = ei + NE;

    // ---- read this block's edges once (coalesced) ----
    int myd[4], mys[4];
#pragma unroll
    for (int i = 0; i < 4; ++i) {
        int e = ebase + tid + i * 1024;
        myd[i] = dstA[e] - gbase;
        mys[i] = srcA[e] - gbase;
    }

    // ---- CSR-by-dst build (si = counts, anode = scan, kept = cursor) ----
    if (tid < NPG) sm.si[tid] = 0;
    __syncthreads();
#pragma unroll
    for (int i = 0; i < 4; ++i) atomicAdd(&sm.si[myd[i]], 1);
    __syncthreads();
    if (tid < NPG) sm.anode[tid] = sm.si[tid];
    __syncthreads();
    for (int o = 1; o < NPG; o <<= 1) {
        int add = 0;
        if (tid < NPG && tid >= o) add = sm.anode[tid - o];
        __syncthreads();
        if (tid < NPG) sm.anode[tid] += add;
        __syncthreads();
    }
    if (tid < NPG) {
        int excl = sm.anode[tid] - sm.si[tid];
        sm.rp[tid] = excl;
        sm.kept[tid] = excl;
        if (tid == 0) sm.rp[NPG] = EPG;
    }
    __syncthreads();
#pragma unroll
    for (int i = 0; i < 4; ++i) {
        int p = atomicAdd(&sm.kept[myd[i]], 1);
        sm.colb[p] = (unsigned char)mys[i];      // LOCAL src id as byte
    }

    // ---- stage x -> LDS; init active set and readout accumulator ----
    {
        const int r0 = tid >> 5, f4 = tid & 31;
        for (int r = r0; r < NPG; r += NSL)
            *(float4*)&sm.hs[r][4 * f4] =
                *(const float4*)&x[((size_t)(gbase + r)) * FD + 4 * f4];
    }
    if (tid < NPG) { sm.anode[tid] = tid; sm.nmloc[tid] = 1.f; }
    if (tid < 2 * FD) sm.zacc[tid] = 0.f;
    __syncthreads();   // colb + hs + state visible block-wide

    do_level<256>(sm, W1, b1, Wp1, bp1, tid);
    do_level<128>(sm, W2, b2, Wp2, bp2, tid);
    do_level<64>(sm, W3, b3, Wp3, bp3, tid);

    // ---- final MLP + log_softmax (reuse sw/sf/svv as h1/h2/logits) ----
    if (tid < 128) {
        float a = bl1[tid];
#pragma unroll 8
        for (int k = 0; k < 256; ++k) a += sm.zacc[k] * Wl1[k * 128 + tid];
        sm.sw[tid] = fmaxf(a, 0.f);
    }
    __syncthreads();
    if (tid < 64) {
        float a = bl2[tid];
#pragma unroll 8
        for (int k = 0; k < 128; ++k) a += sm.sw[k] * Wl2[k * 64 + tid];
        sm.sf[tid] = fmaxf(a, 0.f);
    }
    __syncthreads();
    if (tid < NC) {
        float a = bl3[tid];
#pragma unroll
        for (int k = 0; k < 64; ++k) a += sm.sf[k] * Wl3[k * NC + tid];
        sm.svv[tid] = a;
    }
    __syncthreads();
    if (tid == 0) {
        float m = sm.svv[0];
        for (int c = 1; c < NC; ++c) m = fmaxf(m, sm.svv[c]);
        float se = 0.f;
        for (int c = 0; c < NC; ++c) se += expf(sm.svv[c] - m);
        float lse = m + logf(se);
        for (int c = 0; c < NC; ++c) out[g * NC + c] = sm.svv[c] - lse;
    }
}

// ---------------------------------------------------------------------------
extern "C" void kernel_launch(void* const* d_in, const int* in_sizes, int n_in,
                              void* d_out, int out_size, void* d_ws, size_t ws_size,
                              hipStream_t stream) {
    const float* x   = (const float*)d_in[0];
    const int*   ei  = (const int*)d_in[1];
    const float* W1  = (const float*)d_in[3];
    const float* b1  = (const float*)d_in[4];
    const float* Wp1 = (const float*)d_in[5];
    const float* bp1 = (const float*)d_in[6];
    const float* W2  = (const float*)d_in[7];
    const float* b2  = (const float*)d_in[8];
    const float* Wp2 = (const float*)d_in[9];
    const float* bp2 = (const float*)d_in[10];
    const float* W3  = (const float*)d_in[11];
    const float* b3  = (const float*)d_in[12];
    const float* Wp3 = (const float*)d_in[13];
    const float* bp3 = (const float*)d_in[14];
    const float* Wl1 = (const float*)d_in[15];
    const float* bl1 = (const float*)d_in[16];
    const float* Wl2 = (const float*)d_in[17];
    const float* bl2 = (const float*)d_in[18];
    const float* Wl3 = (const float*)d_in[19];
    const float* bl3 = (const float*)d_in[20];
    float* out = (float*)d_out;

    k_mega<<<NB, 1024, 0, stream>>>(x, ei,
                                    W1, b1, Wp1, bp1,
                                    W2, b2, Wp2, bp2,
                                    W3, b3, Wp3, bp3,
                                    Wl1, bl1, Wl2, bl2, Wl3, bl3, out);
}

// Round 6
// 126.996 us; speedup vs baseline: 3.9894x; 1.3030x over previous
//
#include <hip/hip_runtime.h>
#include <math.h>

// Problem constants (fixed by the reference)
#define NB   256                 // graphs
#define NPG  256                 // nodes per graph
#define NN   (NB * NPG)          // 65536 nodes
#define NE   (NN * 16)           // 1048576 edges
#define EPG  (NE / NB)           // 4096 edges per graph
#define FD   128                 // F == H
#define NC   10
#define NSL  32                  // slices (1024 threads / 32 lanes-per-slice)
#define NEG_INF (-3.402823466e38f)

// Shared-memory layout for the fused per-graph block: ~163 KB <= 160 KiB.
struct SM {
    float hs[NPG][FD];          // 128 KB: x -> hW -> gated h (in place across levels)
    int   rp[NPG + 4];          // local CSR row pointers
    float nmloc[NPG];           // node mask
    float dvv[NPG];             // dinv
    float sw[NPG];              // score matvec result
    float sf[NPG];              // score conv result (by node id)
    float svv[NPG];             // sort staging / MLP logits buffer
    float th[NPG];              // tanh(score) for kept
    float zacc[2 * FD];         // readout accumulator across levels
    int   si[NPG];              // sort staging / CSR counts
    int   kept[NPG];            // kept flags / CSR scatter cursor
    int   anode[NPG];           // active list / CSR scan buffer
    float red_mx[16][FD];       // per-wave readout partials
    float red_sm[16][FD];
    unsigned char colb[EPG];    // edge src local ids (CSR-by-dst order), 4 KB
};

// Swizzled access to feature-quad q (16B) of row v: physical quad = q ^ (v&7).
// Banks repeat every 8 quads, so this de-aliases different rows accessed at
// the same feature offset by the two half-waves of a wave64.
__device__ __forceinline__ float4& hsq(SM& sm, int v, int q) {
    return *(float4*)&sm.hs[v][(q ^ (v & 7)) << 2];
}

// ---------------------------------------------------------------------------
// One pooling level, fully in-LDS. NACT = active node count (256/128/64).
// Thread layout: f4 = tid&31 (feature quad), s = tid>>5 (slice 0..31);
// slice s owns active indices i = c*32+s, c < NPS = NACT/32.
// ---------------------------------------------------------------------------
template <int NACT>
__device__ __forceinline__ void do_level(SM& sm,
                                         const float* __restrict__ Wmat,
                                         const float* __restrict__ bias,
                                         const float* __restrict__ Wp,
                                         const float* __restrict__ bpp,
                                         int tid) {
    constexpr int NPS = NACT / NSL;
    constexpr int K   = NACT / 2;
    constexpr int TPN = 1024 / NACT;     // threads per node in score conv
    const int f4 = tid & 31;
    const int s  = tid >> 5;

    // ---- dinv: 4 threads per node (all 1024 threads active) ----
    {
        const int n = tid >> 2, sub = tid & 3;
        float part = 0.f;
        const float nmn = sm.nmloc[n];
        if (nmn > 0.f) {
            const int e1 = sm.rp[n + 1];
            for (int e = sm.rp[n] + sub; e < e1; e += 4)
                part += sm.nmloc[sm.colb[e]];
        }
        part += __shfl_xor(part, 1);
        part += __shfl_xor(part, 2);
        if (sub == 0)
            sm.dvv[n] = (nmn > 0.f) ? rsqrtf(1.f + part) : 0.f;
    }

    // ---- in-place GEMM on active rows: hs[v] <- hs[v] @ W ----
    // Row v is read and written only by the 32 lanes of the half-wave that
    // owns it (lockstep) -> no barrier needed around the in-place update.
    {
        int vr[NPS];
        float4 acc[NPS];
#pragma unroll
        for (int c = 0; c < NPS; ++c) {
            vr[c] = sm.anode[c * NSL + s];
            acc[c] = make_float4(0.f, 0.f, 0.f, 0.f);
        }
#pragma unroll 2
        for (int kq = 0; kq < 32; ++kq) {
            const int k0 = kq << 2;
            float4 w0 = *(const float4*)&Wmat[(k0 + 0) * FD + 4 * f4];
            float4 w1 = *(const float4*)&Wmat[(k0 + 1) * FD + 4 * f4];
            float4 w2 = *(const float4*)&Wmat[(k0 + 2) * FD + 4 * f4];
            float4 w3 = *(const float4*)&Wmat[(k0 + 3) * FD + 4 * f4];
#pragma unroll
            for (int c = 0; c < NPS; ++c) {
                float4 hv = hsq(sm, vr[c], kq);
                acc[c].x += hv.x * w0.x + hv.y * w1.x + hv.z * w2.x + hv.w * w3.x;
                acc[c].y += hv.x * w0.y + hv.y * w1.y + hv.z * w2.y + hv.w * w3.y;
                acc[c].z += hv.x * w0.z + hv.y * w1.z + hv.z * w2.z + hv.w * w3.z;
                acc[c].w += hv.x * w0.w + hv.y * w1.w + hv.z * w2.w + hv.w * w3.w;
            }
        }
#pragma unroll
        for (int c = 0; c < NPS; ++c)
            hsq(sm, vr[c], f4) = acc[c];
    }
    __syncthreads();   // publishes GEMM rows + dvv

    // ---- conv + relu + fused score matvec (active nodes only) ----
    const float4 b4  = *(const float4*)&bias[4 * f4];
    const float4 wp4 = *(const float4*)&Wp[4 * f4];
    float4 hreg[NPS];
#pragma unroll
    for (int c = 0; c < NPS; ++c) {
        const int v = sm.anode[c * NSL + s];
        const float dv_ = sm.dvv[v], dv2 = dv_ * dv_;
        const float4 hv = hsq(sm, v, f4);
        float4 acc;
        acc.x = hv.x * dv2 + b4.x;
        acc.y = hv.y * dv2 + b4.y;
        acc.z = hv.z * dv2 + b4.z;
        acc.w = hv.w * dv2 + b4.w;
        const int e0 = sm.rp[v], e1 = sm.rp[v + 1];
        int e = e0;
        for (; e + 4 <= e1; e += 4) {
            int u0 = sm.colb[e],     u1 = sm.colb[e + 1];
            int u2 = sm.colb[e + 2], u3 = sm.colb[e + 3];
            float w0 = sm.dvv[u0] * dv_, w1 = sm.dvv[u1] * dv_;
            float w2 = sm.dvv[u2] * dv_, w3 = sm.dvv[u3] * dv_;
            float4 h0 = hsq(sm, u0, f4);
            float4 h1 = hsq(sm, u1, f4);
            float4 h2 = hsq(sm, u2, f4);
            float4 h3 = hsq(sm, u3, f4);
            acc.x += w0 * h0.x + w1 * h1.x + w2 * h2.x + w3 * h3.x;
            acc.y += w0 * h0.y + w1 * h1.y + w2 * h2.y + w3 * h3.y;
            acc.z += w0 * h0.z + w1 * h1.z + w2 * h2.z + w3 * h3.z;
            acc.w += w0 * h0.w + w1 * h1.w + w2 * h2.w + w3 * h3.w;
        }
        for (; e < e1; ++e) {
            int u = sm.colb[e];
            float w = sm.dvv[u] * dv_;
            float4 hu = hsq(sm, u, f4);
            acc.x += w * hu.x; acc.y += w * hu.y;
            acc.z += w * hu.z; acc.w += w * hu.w;
        }
        acc.x = fmaxf(acc.x, 0.f);
        acc.y = fmaxf(acc.y, 0.f);
        acc.z = fmaxf(acc.z, 0.f);
        acc.w = fmaxf(acc.w, 0.f);
        hreg[c] = acc;
        // score partial: dot(h[v], Wp) reduced across the 32 f4 lanes
        float p = acc.x * wp4.x + acc.y * wp4.y + acc.z * wp4.z + acc.w * wp4.w;
        p += __shfl_xor(p, 1);
        p += __shfl_xor(p, 2);
        p += __shfl_xor(p, 4);
        p += __shfl_xor(p, 8);
        p += __shfl_xor(p, 16);
        if (f4 == 0) sm.sw[v] = p;
    }
    __syncthreads();

    // ---- score conv: TPN threads per active node (all lanes busy) ----
    {
        const int i = tid / TPN, sub = tid % TPN;
        const int v = sm.anode[i];
        const float dv_ = sm.dvv[v];
        float part = 0.f;
        const int e1 = sm.rp[v + 1];
        for (int e = sm.rp[v] + sub; e < e1; e += TPN) {
            int u = sm.colb[e];
            part += sm.dvv[u] * sm.sw[u];
        }
#pragma unroll
        for (int o = 1; o < TPN; o <<= 1) part += __shfl_xor(part, o);
        if (sub == 0) {
            float acc = sm.sw[v] * dv_ * dv_ + bpp[0] + dv_ * part;
            sm.sf[v] = acc;        // by node id (for tanh later)
            sm.svv[i] = acc;       // by active index (for sort)
        }
    }
    __syncthreads();

    // ---- bitonic sort of NACT active elements, registers + shuffles ----
    // comparator: value desc, node-id asc  (= jax.lax.top_k semantics)
    float v_ = 0.f;
    int   id_ = 0;
    if (tid < NACT) { v_ = sm.svv[tid]; id_ = sm.anode[tid]; }
#pragma unroll
    for (int k = 2; k <= NACT; k <<= 1) {
#pragma unroll
        for (int j = k >> 1; j > 0; j >>= 1) {
            if (j < 64) {
                if (tid < NACT) {
                    float vp = __shfl_xor(v_, j);
                    int  idp = __shfl_xor(id_, j);
                    bool up    = ((tid & k) == 0);
                    bool lower = ((tid & j) == 0);
                    bool g = (v_ > vp) || (v_ == vp && id_ < idp);
                    if (g != (lower == up)) { v_ = vp; id_ = idp; }
                }
            } else {
                if (tid < NACT) { sm.svv[tid] = v_; sm.si[tid] = id_; }
                __syncthreads();
                if (tid < NACT) {
                    int p = tid ^ j;
                    float vp = sm.svv[p];
                    int  idp = sm.si[p];
                    bool up    = ((tid & k) == 0);
                    bool lower = ((tid & j) == 0);
                    bool g = (v_ > vp) || (v_ == vp && id_ < idp);
                    if (g != (lower == up)) { v_ = vp; id_ = idp; }
                }
                __syncthreads();
            }
        }
    }
    if (tid < NPG) sm.kept[tid] = 0;
    __syncthreads();
    if (tid < K) {
        sm.kept[id_] = 1;
        sm.th[id_] = tanhf(sm.sf[id_]);
    }
    __syncthreads();

    // ---- tanh-gate: write kept rows back into hs; readout partials ----
    float4 mx4 = make_float4(NEG_INF, NEG_INF, NEG_INF, NEG_INF);
    float4 sm4 = make_float4(0.f, 0.f, 0.f, 0.f);
#pragma unroll
    for (int c = 0; c < NPS; ++c) {
        const int v = sm.anode[c * NSL + s];
        if (sm.kept[v]) {
            const float tg = sm.th[v];
            float4 val;
            val.x = hreg[c].x * tg;
            val.y = hreg[c].y * tg;
            val.z = hreg[c].z * tg;
            val.w = hreg[c].w * tg;
            hsq(sm, v, f4) = val;
            mx4.x = fmaxf(mx4.x, val.x); sm4.x += val.x;
            mx4.y = fmaxf(mx4.y, val.y); sm4.y += val.y;
            mx4.z = fmaxf(mx4.z, val.z); sm4.z += val.z;
            mx4.w = fmaxf(mx4.w, val.w); sm4.w += val.w;
        }
    }
    mx4.x = fmaxf(mx4.x, __shfl_xor(mx4.x, 32)); sm4.x += __shfl_xor(sm4.x, 32);
    mx4.y = fmaxf(mx4.y, __shfl_xor(mx4.y, 32)); sm4.y += __shfl_xor(sm4.y, 32);
    mx4.z = fmaxf(mx4.z, __shfl_xor(mx4.z, 32)); sm4.z += __shfl_xor(sm4.z, 32);
    mx4.w = fmaxf(mx4.w, __shfl_xor(mx4.w, 32)); sm4.w += __shfl_xor(sm4.w, 32);
    const int wv = tid >> 6;
    if ((tid & 63) < 32) {
        *(float4*)&sm.red_mx[wv][4 * f4] = mx4;
        *(float4*)&sm.red_sm[wv][4 * f4] = sm4;
    }
    __syncthreads();   // all threads done with gate loop + red writes
    if (tid < FD) {
        float mx = NEG_INF, smv = 0.f;
#pragma unroll
        for (int i = 0; i < 16; ++i) {
            mx = fmaxf(mx, sm.red_mx[i][tid]);
            smv += sm.red_sm[i][tid];
        }
        sm.zacc[tid] += mx;
        sm.zacc[FD + tid] += smv / (float)K;
    }
    // ---- update active set for next level ----
    if (tid < NPG) sm.nmloc[tid] = (float)sm.kept[tid];
    if (tid < K) sm.anode[tid] = id_;
    __syncthreads();
}

// ---------------------------------------------------------------------------
// Fully-fused kernel: one 1024-thread block per graph does CSR build, all
// 3 GCN+pool levels, readout, and the final MLP + log_softmax.
// ---------------------------------------------------------------------------
__global__ __launch_bounds__(1024)
void k_mega(const float* __restrict__ x, const int* __restrict__ ei,
            const float* __restrict__ W1, const float* __restrict__ b1,
            const float* __restrict__ Wp1, const float* __restrict__ bp1,
            const float* __restrict__ W2, const float* __restrict__ b2,
            const float* __restrict__ Wp2, const float* __restrict__ bp2,
            const float* __restrict__ W3, const float* __restrict__ b3,
            const float* __restrict__ Wp3, const float* __restrict__ bp3,
            const float* __restrict__ Wl1, const float* __restrict__ bl1,
            const float* __restrict__ Wl2, const float* __restrict__ bl2,
            const float* __restrict__ Wl3, const float* __restrict__ bl3,
            float* __restrict__ out) {
    __shared__ SM sm;
    const int g = blockIdx.x, tid = threadIdx.x;
    const int gbase = g * NPG, ebase = g * EPG;
    const int* __restrict__ srcA = ei;
    const int* __restrict__ dstA = ei + NE;

    // ---- read this block's edges once (coalesced) ----
    int myd[4], mys[4];
#pragma unroll
    for (int i = 0; i < 4; ++i) {
        int e = ebase + tid + i * 1024;
        myd[i] = dstA[e] - gbase;
        mys[i] = srcA[e] - gbase;
    }

    // ---- CSR-by-dst build (si = counts, anode = scan, kept = cursor) ----
    if (tid < NPG) sm.si[tid] = 0;
    __syncthreads();
#pragma unroll
    for (int i = 0; i < 4; ++i) atomicAdd(&sm.si[myd[i]], 1);
    __syncthreads();
    if (tid < NPG) sm.anode[tid] = sm.si[tid];
    __syncthreads();
    for (int o = 1; o < NPG; o <<= 1) {
        int add = 0;
        if (tid < NPG && tid >= o) add = sm.anode[tid - o];
        __syncthreads();
        if (tid < NPG) sm.anode[tid] += add;
        __syncthreads();
    }
    if (tid < NPG) {
        int excl = sm.anode[tid] - sm.si[tid];
        sm.rp[tid] = excl;
        sm.kept[tid] = excl;
        if (tid == 0) sm.rp[NPG] = EPG;
    }
    __syncthreads();
#pragma unroll
    for (int i = 0; i < 4; ++i) {
        int p = atomicAdd(&sm.kept[myd[i]], 1);
        sm.colb[p] = (unsigned char)mys[i];      // LOCAL src id as byte
    }

    // ---- stage x -> LDS (swizzled); init active set + readout acc ----
    {
        const int r0 = tid >> 5, f4 = tid & 31;
        for (int r = r0; r < NPG; r += NSL)
            hsq(sm, r, f4) =
                *(const float4*)&x[((size_t)(gbase + r)) * FD + 4 * f4];
    }
    if (tid < NPG) { sm.anode[tid] = tid; sm.nmloc[tid] = 1.f; }
    if (tid < 2 * FD) sm.zacc[tid] = 0.f;
    __syncthreads();   // colb + hs + state visible block-wide

    do_level<256>(sm, W1, b1, Wp1, bp1, tid);
    do_level<128>(sm, W2, b2, Wp2, bp2, tid);
    do_level<64>(sm, W3, b3, Wp3, bp3, tid);

    // ---- final MLP + log_softmax (reuse sw/sf/svv as h1/h2/logits) ----
    if (tid < 128) {
        float a = bl1[tid];
#pragma unroll 8
        for (int k = 0; k < 256; ++k) a += sm.zacc[k] * Wl1[k * 128 + tid];
        sm.sw[tid] = fmaxf(a, 0.f);
    }
    __syncthreads();
    if (tid < 64) {
        float a = bl2[tid];
#pragma unroll 8
        for (int k = 0; k < 128; ++k) a += sm.sw[k] * Wl2[k * 64 + tid];
        sm.sf[tid] = fmaxf(a, 0.f);
    }
    __syncthreads();
    if (tid < NC) {
        float a = bl3[tid];
#pragma unroll
        for (int k = 0; k < 64; ++k) a += sm.sf[k] * Wl3[k * NC + tid];
        sm.svv[tid] = a;
    }
    __syncthreads();
    if (tid == 0) {
        float m = sm.svv[0];
        for (int c = 1; c < NC; ++c) m = fmaxf(m, sm.svv[c]);
        float se = 0.f;
        for (int c = 0; c < NC; ++c) se += expf(sm.svv[c] - m);
        float lse = m + logf(se);
        for (int c = 0; c < NC; ++c) out[g * NC + c] = sm.svv[c] - lse;
    }
}

// ---------------------------------------------------------------------------
extern "C" void kernel_launch(void* const* d_in, const int* in_sizes, int n_in,
                              void* d_out, int out_size, void* d_ws, size_t ws_size,
                              hipStream_t stream) {
    const float* x   = (const float*)d_in[0];
    const int*   ei  = (const int*)d_in[1];
    const float* W1  = (const float*)d_in[3];
    const float* b1  = (const float*)d_in[4];
    const float* Wp1 = (const float*)d_in[5];
    const float* bp1 = (const float*)d_in[6];
    const float* W2  = (const float*)d_in[7];
    const float* b2  = (const float*)d_in[8];
    const float* Wp2 = (const float*)d_in[9];
    const float* bp2 = (const float*)d_in[10];
    const float* W3  = (const float*)d_in[11];
    const float* b3  = (const float*)d_in[12];
    const float* Wp3 = (const float*)d_in[13];
    const float* bp3 = (const float*)d_in[14];
    const float* Wl1 = (const float*)d_in[15];
    const float* bl1 = (const float*)d_in[16];
    const float* Wl2 = (const float*)d_in[17];
    const float* bl2 = (const float*)d_in[18];
    const float* Wl3 = (const float*)d_in[19];
    const float* bl3 = (const float*)d_in[20];
    float* out = (float*)d_out;

    k_mega<<<NB, 1024, 0, stream>>>(x, ei,
                                    W1, b1, Wp1, bp1,
                                    W2, b2, Wp2, bp2,
                                    W3, b3, Wp3, bp3,
                                    Wl1, bl1, Wl2, bl2, Wl3, bl3, out);
}